// Round 9
// baseline (358.325 us; speedup 1.0000x reference)
//
#include <hip/hip_runtime.h>
#include <hip/hip_bf16.h>
#include <stdint.h>

#define B_ 2
#define N_ 4096
#define D_ 128
#define H_ 4
#define HID_ 32
#define EN_ 16
#define ALPHA_ 0.2f
#define S1_ 4          // split-K factor, layer-1 attention
#define S2_ 4          // split-K factor, layer-2 attention
#define LOG2E_ 1.4426950408889634f

typedef __attribute__((ext_vector_type(8))) _Float16 f16x8;
typedef __attribute__((ext_vector_type(4))) float f32x4;
typedef __attribute__((ext_vector_type(8))) unsigned short u16x8;

// monotonic float->uint key for atomicMax over signed floats
__device__ __forceinline__ unsigned int f2key(float x) {
    unsigned int u = __float_as_uint(x);
    return (u & 0x80000000u) ? ~u : (u | 0x80000000u);
}
__device__ __forceinline__ float key2f(unsigned int k) {
    unsigned int u = (k & 0x80000000u) ? (k ^ 0x80000000u) : ~k;
    return __uint_as_float(u);
}
__device__ __forceinline__ unsigned short f2h(float v) {
    _Float16 h = (_Float16)v;
    return *(unsigned short*)&h;
}

// ---------- adj -> bitmask compression: mask[b][i][w] bit l = (adj[b][i][w*64+l] != 0)
__global__ __launch_bounds__(256) void maskc_kernel(
    const float* __restrict__ adj, unsigned long long* __restrict__ mask)
{
    const int b = blockIdx.y;
    const int i = blockIdx.x * 4 + (threadIdx.x >> 6);
    const int lane = threadIdx.x & 63;
    const float* ar = adj + ((size_t)b * N_ + i) * N_;
    unsigned long long* mrow = mask + ((size_t)b * N_ + i) * 64;
    for (int w0 = 0; w0 < 16; ++w0) {
        float v0 = ar[(w0 +  0) * 64 + lane];
        float v1 = ar[(w0 + 16) * 64 + lane];
        float v2 = ar[(w0 + 32) * 64 + lane];
        float v3 = ar[(w0 + 48) * 64 + lane];
        unsigned long long b0 = __ballot(v0 != 0.f);
        unsigned long long b1 = __ballot(v1 != 0.f);
        unsigned long long b2 = __ballot(v2 != 0.f);
        unsigned long long b3 = __ballot(v3 != 0.f);
        if (lane == 0) {
            mrow[w0] = b0; mrow[w0 + 16] = b1; mrow[w0 + 32] = b2; mrow[w0 + 48] = b3;
        }
    }
}

// ---------- layer-1 projection: wh[b][h][i][d] = fea[b][i][:] @ W_heads[h][:][d]
__global__ __launch_bounds__(256) void proj1_kernel(
    const float* __restrict__ fea, const float* __restrict__ Wh,
    float* __restrict__ wh)
{
    __shared__ float Ws[D_ * HID_];   // 16 KB
    __shared__ float xs[8][D_];       // 4 KB
    const int b = blockIdx.z, h = blockIdx.y;
    const int i0 = blockIdx.x * 8;
    const int tid = threadIdx.x;
    const float* Wp = Wh + h * D_ * HID_;
    for (int idx = tid * 4; idx < D_ * HID_; idx += 1024)
        *(float4*)&Ws[idx] = *(const float4*)(Wp + idx);
    const float* xp = fea + ((size_t)b * N_ + i0) * D_;
    *(float4*)&xs[(tid * 4) >> 7][(tid * 4) & 127] = *(const float4*)(xp + tid * 4);
    __syncthreads();
    const int r = tid >> 5, d = tid & 31;
    float acc = 0.f;
#pragma unroll 8
    for (int k = 0; k < D_; ++k) acc += xs[r][k] * Ws[k * HID_ + d];
    wh[(((size_t)b * H_ + h) * N_ + i0 + r) * HID_ + d] = acc;
}

// ---------- layer-1: wh1, wh2 (scaled by log2e), per-(b,h) max, f16 whTt[b][h][jblk][32][64]
__global__ __launch_bounds__(128) void proj1b_kernel(
    const float* __restrict__ wh, const float* __restrict__ a_heads,
    float* __restrict__ wh1, float* __restrict__ wh2,
    unsigned int* __restrict__ mkey, unsigned short* __restrict__ whTt)
{
    __shared__ float as_[2 * HID_];
    __shared__ unsigned short ts[32][136];   // row = 272 B (16-aligned for b128)
    const int b = blockIdx.z, h = blockIdx.y, tid = threadIdx.x;
    const int i = blockIdx.x * 128 + tid;
    if (tid < 2 * HID_) as_[tid] = a_heads[h * 2 * HID_ + tid];
    __syncthreads();
    const float* row = wh + (((size_t)b * H_ + h) * N_ + i) * HID_;
    float rv[32];
#pragma unroll
    for (int q = 0; q < 8; ++q) *(float4*)&rv[q * 4] = ((const float4*)row)[q];
    float a1 = 0.f, a2 = 0.f;
#pragma unroll
    for (int d = 0; d < HID_; ++d) {
        float v = rv[d];
        a1 += v * as_[d]; a2 += v * as_[HID_ + d];
        ts[d][tid] = f2h(v);
    }
    a1 *= LOG2E_; a2 *= LOG2E_;     // prescale: exp(x) -> exp2(x'), lrelu is +scale-invariant
    const size_t o = (size_t)(b * H_ + h) * N_ + i;
    wh1[o] = a1; wh2[o] = a2;
    float m = a2;
#pragma unroll
    for (int off = 32; off; off >>= 1) m = fmaxf(m, __shfl_xor(m, off));
    if ((tid & 63) == 0) atomicMax(&mkey[b * H_ + h], f2key(m));
    __syncthreads();
    const size_t base = ((size_t)(b * H_ + h) * 64 + blockIdx.x * 2) * 2048;
#pragma unroll
    for (int r = 0; r < 4; ++r) {
        int l = r * 128 + tid;               // 0..511
        int jb = l >> 8, d = (l >> 3) & 31, part = l & 7;
        *(u16x8*)(whTt + base + (size_t)jb * 2048 + d * 64 + part * 8) =
            *(const u16x8*)&ts[d][jb * 64 + part * 8];
    }
}

// ---------- layer-1 fused MFMA attention: bitmask-gated, barrier-free K-loop.
// block 256 = 4 waves (one per head), 16 rows/block, split-K atomics.
// Denominator via all-ones third MFMA (acc2) -- exactly consistent with numerator.
__global__ __launch_bounds__(256) void attn1_kernel(
    const unsigned long long* __restrict__ mask, const unsigned short* __restrict__ whT,
    const float* __restrict__ wh1, const float* __restrict__ wh2,
    const unsigned int* __restrict__ mkey,
    float* __restrict__ x2num, float* __restrict__ l1sum)
{
    __shared__ unsigned long long mask_s[16][17];    // padded: conflict-free reads
    const int b = blockIdx.z, split = blockIdx.y, i0 = blockIdx.x * 16;
    const int tid = threadIdx.x, lane = tid & 63, h = tid >> 6;   // wave = head
    const int m = lane & 15, quad = lane >> 4;
    mask_s[tid >> 4][tid & 15] =
        mask[((size_t)b * N_ + i0 + (tid >> 4)) * 64 + split * 16 + (tid & 15)];
    const float w1r = wh1[(size_t)(b * H_ + h) * N_ + i0 + m];
    const float Mh = key2f(mkey[b * H_ + h]);
    const float sbound = w1r + Mh;
    const float mr = fmaxf(sbound, ALPHA_ * sbound); // lrelu == max(s, 0.2s)
    const float* w2h = wh2 + (size_t)(b * H_ + h) * N_;
    const unsigned short* whTp = whT + (size_t)(b * H_ + h) * 64 * 2048;
    f32x4 acc0 = {0.f, 0.f, 0.f, 0.f}, acc1 = {0.f, 0.f, 0.f, 0.f};
    f32x4 acc2 = {0.f, 0.f, 0.f, 0.f};
    f16x8 ones;
#pragma unroll
    for (int q = 0; q < 8; ++q) ones[q] = (_Float16)1.0f;
    const int jt0 = split * (N_ / S1_);
    __syncthreads();                                 // mask_s ready; no barriers after

    for (int t = 0; t < N_ / S1_ / 64; ++t) {        // 16 tiles of 64 j
        const int jt = jt0 + t * 64;
        const int jb = split * 16 + t;
        unsigned long long wrd = mask_s[m][t];
        unsigned int mh2[2] = {(unsigned int)wrd, (unsigned int)(wrd >> 32)};
#pragma unroll
        for (int ks = 0; ks < 2; ++ks) {
            const int ko = ks * 32 + quad * 8;
            const unsigned int mby = mh2[ks];
            float wv8[8];
            *(float4*)&wv8[0] = *(const float4*)(w2h + jt + ko);
            *(float4*)&wv8[4] = *(const float4*)(w2h + jt + ko + 4);
            f16x8 af;
#pragma unroll
            for (int q = 0; q < 4; ++q) {
                float p2[2];
#pragma unroll
                for (int c = 0; c < 2; ++c) {
                    int jj = q * 2 + c;
                    float s = w1r + wv8[jj];
                    float e = fmaxf(s, ALPHA_ * s);
                    float tt = e - mr;
                    unsigned int bit = (mby >> (quad * 8 + jj)) & 1u;
                    tt = (bit == 0u || s == 0.f) ? -1e38f : tt;
                    p2[c] = __builtin_amdgcn_exp2f(tt);
                }
                auto pr = __builtin_amdgcn_cvt_pkrtz(p2[0], p2[1]);   // __fp16 x2
                af[q * 2] = (_Float16)pr[0]; af[q * 2 + 1] = (_Float16)pr[1];
            }
            const unsigned short* bp = whTp + (size_t)jb * 2048 + m * 64 + ks * 32 + quad * 8;
            f16x8 b0 = *(const f16x8*)bp;
            f16x8 b1 = *(const f16x8*)(bp + 1024);   // d = m+16
            acc0 = __builtin_amdgcn_mfma_f32_16x16x32_f16(af, b0, acc0, 0, 0, 0);
            acc1 = __builtin_amdgcn_mfma_f32_16x16x32_f16(af, b1, acc1, 0, 0, 0);
            acc2 = __builtin_amdgcn_mfma_f32_16x16x32_f16(af, ones, acc2, 0, 0, 0);
        }
    }
#pragma unroll
    for (int reg = 0; reg < 4; ++reg) {
        int row = quad * 4 + reg;                    // C/D: col=lane&15, row=quad*4+reg
        float* dst = x2num + ((size_t)b * N_ + i0 + row) * (H_ * HID_) + h * HID_;
        atomicAdd(dst + m, acc0[reg]);
        atomicAdd(dst + 16 + m, acc1[reg]);
        if (m == 0)                                  // acc2 cols identical; col 0 reports
            atomicAdd(l1sum + ((size_t)b * N_ + i0 + row) * H_ + h, acc2[reg]);
    }
}

// ---------- layer-2 projection with fused layer-1 finalize: whl2 = elu(x2num/l1) @ W_last
__global__ __launch_bounds__(256) void proj2_kernel(
    const float* __restrict__ x2num, const float* __restrict__ l1sum,
    const float* __restrict__ Wl, float* __restrict__ whl2)
{
    __shared__ float Ws[D_ * EN_];
    __shared__ float xs[16][D_];
    const int b = blockIdx.y, i0 = blockIdx.x * 16, tid = threadIdx.x;
    for (int idx = tid * 4; idx < D_ * EN_; idx += 1024)
        *(float4*)&Ws[idx] = *(const float4*)(Wl + idx);
    for (int idx = tid * 4; idx < 16 * D_; idx += 1024) {
        int r = idx >> 7, hd = idx & 127, h = hd >> 5;
        const size_t i = (size_t)b * N_ + i0 + r;
        float linv = 1.f / fmaxf(l1sum[i * H_ + h], 1e-30f);
        float4 v = *(const float4*)(x2num + i * D_ + hd);
        float o0 = v.x * linv, o1 = v.y * linv, o2 = v.z * linv, o3 = v.w * linv;
        xs[r][hd]     = o0 > 0.f ? o0 : expm1f(o0);
        xs[r][hd + 1] = o1 > 0.f ? o1 : expm1f(o1);
        xs[r][hd + 2] = o2 > 0.f ? o2 : expm1f(o2);
        xs[r][hd + 3] = o3 > 0.f ? o3 : expm1f(o3);
    }
    __syncthreads();
    const int r = tid >> 4, e = tid & 15;
    float acc = 0.f;
#pragma unroll 8
    for (int k = 0; k < D_; ++k) acc += xs[r][k] * Ws[k * EN_ + e];
    whl2[((size_t)b * N_ + i0 + r) * EN_ + e] = acc;
}

// ---------- layer-2: wh1b, wh2b (scaled), per-b max, f16 whT2t[b][jblk][16][64]
__global__ __launch_bounds__(128) void proj2b_kernel(
    const float* __restrict__ whl2, const float* __restrict__ a_last,
    float* __restrict__ wh1b, float* __restrict__ wh2b,
    unsigned int* __restrict__ mkey2, unsigned short* __restrict__ whT2t)
{
    __shared__ float as_[2 * EN_];
    __shared__ unsigned short ts[16][136];   // row = 272 B (16-aligned)
    const int b = blockIdx.y, tid = threadIdx.x;
    const int i = blockIdx.x * 128 + tid;
    if (tid < 2 * EN_) as_[tid] = a_last[tid];
    __syncthreads();
    const float* row = whl2 + ((size_t)b * N_ + i) * EN_;
    float rv[16];
#pragma unroll
    for (int q = 0; q < 4; ++q) *(float4*)&rv[q * 4] = ((const float4*)row)[q];
    float a1 = 0.f, a2 = 0.f;
#pragma unroll
    for (int e = 0; e < EN_; ++e) {
        float v = rv[e];
        a1 += v * as_[e]; a2 += v * as_[EN_ + e];
        ts[e][tid] = f2h(v);
    }
    a1 *= LOG2E_; a2 *= LOG2E_;
    wh1b[(size_t)b * N_ + i] = a1; wh2b[(size_t)b * N_ + i] = a2;
    float m = a2;
#pragma unroll
    for (int off = 32; off; off >>= 1) m = fmaxf(m, __shfl_xor(m, off));
    if ((tid & 63) == 0) atomicMax(mkey2 + b, f2key(m));
    __syncthreads();
    const size_t base = ((size_t)b * 64 + blockIdx.x * 2) * 1024;
#pragma unroll
    for (int r = 0; r < 2; ++r) {
        int l = r * 128 + tid;               // 0..255
        int jb = l >> 7, d = (l >> 3) & 15, part = l & 7;
        *(u16x8*)(whT2t + base + (size_t)jb * 1024 + d * 64 + part * 8) =
            *(const u16x8*)&ts[d][jb * 64 + part * 8];
    }
}

// ---------- layer-2 fused MFMA attention: bitmask-gated, barrier-free.
// block 256 = 4 waves, each wave covers 4 tiles (256 j) of the block's 1024-j split.
__global__ __launch_bounds__(256) void attn2_kernel(
    const unsigned long long* __restrict__ mask, const unsigned short* __restrict__ whT2,
    const float* __restrict__ wh1b, const float* __restrict__ wh2b,
    const unsigned int* __restrict__ mkey2,
    float* __restrict__ out_num, float* __restrict__ out_l)
{
    __shared__ unsigned long long mask_s[16][17];
    const int b = blockIdx.z, split = blockIdx.y, i0 = blockIdx.x * 16;
    const int tid = threadIdx.x, lane = tid & 63, wv = tid >> 6;
    const int m = lane & 15, quad = lane >> 4;
    mask_s[tid >> 4][tid & 15] =
        mask[((size_t)b * N_ + i0 + (tid >> 4)) * 64 + split * 16 + (tid & 15)];
    const float w1r = wh1b[(size_t)b * N_ + i0 + m];
    const float Mh = key2f(mkey2[b]);
    const float sbound = w1r + Mh;
    const float mr = fmaxf(sbound, ALPHA_ * sbound);
    const float* w2g = wh2b + (size_t)b * N_;
    const unsigned short* wTg = whT2 + (size_t)b * 64 * 1024;
    f32x4 acc = {0.f, 0.f, 0.f, 0.f}, acc2 = {0.f, 0.f, 0.f, 0.f};
    f16x8 ones;
#pragma unroll
    for (int q = 0; q < 8; ++q) ones[q] = (_Float16)1.0f;
    const int jt0 = split * (N_ / S2_);
    __syncthreads();

#pragma unroll
    for (int t = 0; t < 4; ++t) {                    // wave's 4 tiles
        const int tw = wv * 4 + t;
        const int jt = jt0 + tw * 64;
        const int jb = split * 16 + tw;
        unsigned long long wrd = mask_s[m][tw];
        unsigned int mh2[2] = {(unsigned int)wrd, (unsigned int)(wrd >> 32)};
#pragma unroll
        for (int ks = 0; ks < 2; ++ks) {
            const int ko = ks * 32 + quad * 8;
            const unsigned int mby = mh2[ks];
            float wv8[8];
            *(float4*)&wv8[0] = *(const float4*)(w2g + jt + ko);
            *(float4*)&wv8[4] = *(const float4*)(w2g + jt + ko + 4);
            f16x8 af;
#pragma unroll
            for (int q = 0; q < 4; ++q) {
                float p2[2];
#pragma unroll
                for (int c = 0; c < 2; ++c) {
                    int jj = q * 2 + c;
                    float s = w1r + wv8[jj];
                    float e = fmaxf(s, ALPHA_ * s);
                    float tt = e - mr;
                    unsigned int bit = (mby >> (quad * 8 + jj)) & 1u;
                    tt = (bit == 0u || s == 0.f) ? -1e38f : tt;
                    p2[c] = __builtin_amdgcn_exp2f(tt);
                }
                auto pr = __builtin_amdgcn_cvt_pkrtz(p2[0], p2[1]);   // __fp16 x2
                af[q * 2] = (_Float16)pr[0]; af[q * 2 + 1] = (_Float16)pr[1];
            }
            f16x8 b0 = *(const f16x8*)(wTg + (size_t)jb * 1024 + m * 64 + ks * 32 + quad * 8);
            acc = __builtin_amdgcn_mfma_f32_16x16x32_f16(af, b0, acc, 0, 0, 0);
            acc2 = __builtin_amdgcn_mfma_f32_16x16x32_f16(af, ones, acc2, 0, 0, 0);
        }
    }
#pragma unroll
    for (int reg = 0; reg < 4; ++reg) {
        int row = quad * 4 + reg;
        atomicAdd(out_num + ((size_t)b * N_ + i0 + row) * EN_ + m, acc[reg]);
        if (m == 0)
            atomicAdd(out_l + (size_t)b * N_ + i0 + row, acc2[reg]);
    }
}

// ---------- final: out = elu(num / l)
__global__ __launch_bounds__(256) void finalize2_kernel(
    const float* __restrict__ num, const float* __restrict__ l, float* __restrict__ out)
{
    const int id = blockIdx.x * 256 + threadIdx.x;      // B*N*EN
    float v = num[id] / fmaxf(l[id >> 4], 1e-30f);
    out[id] = v > 0.f ? v : expm1f(v);
}

extern "C" void kernel_launch(void* const* d_in, const int* in_sizes, int n_in,
                              void* d_out, int out_size, void* d_ws, size_t ws_size,
                              hipStream_t stream)
{
    const float* fea = (const float*)d_in[0];
    const float* adj = (const float*)d_in[1];
    const float* Wh  = (const float*)d_in[2];
    const float* ah  = (const float*)d_in[3];
    const float* Wl  = (const float*)d_in[4];
    const float* al  = (const float*)d_in[5];

    float* ws    = (float*)d_ws;
    float* wh    = ws;                                   // B*H*N*HID = 1,048,576 f
    float* wh1   = wh   + (size_t)B_ * H_ * N_ * HID_;   // 32,768 f
    float* wh2   = wh1  + (size_t)B_ * H_ * N_;          // 32,768 f
    float* whl2  = wh2  + (size_t)B_ * H_ * N_;          // 131,072 f
    float* wh1b  = whl2 + (size_t)B_ * N_ * EN_;         // 8,192 f
    float* wh2b  = wh1b + (size_t)B_ * N_;               // 8,192 f
    // ---- zero region (single memset) ----
    float* x2num  = wh2b + (size_t)B_ * N_;              // B*N*128 = 1,048,576 f
    float* l1sum  = x2num + (size_t)B_ * N_ * D_;        // B*N*H = 32,768 f
    float* outnum = l1sum + (size_t)B_ * N_ * H_;        // B*N*EN = 131,072 f
    float* outl   = outnum + (size_t)B_ * N_ * EN_;      // B*N = 8,192 f
    unsigned int* mkey = (unsigned int*)(outl + (size_t)B_ * N_);  // 16 u32
    size_t zero_bytes = ((size_t)B_ * N_ * (D_ + H_ + EN_ + 1)) * 4 + 64;
    // ---- end zero region ----
    unsigned short* whTt  = (unsigned short*)(mkey + 16);          // f16, 2 MB
    unsigned short* whT2t = whTt + (size_t)B_ * H_ * 64 * 2048;    // f16, 256 KB
    unsigned long long* mask =
        (unsigned long long*)(whT2t + (size_t)B_ * 64 * 1024);     // B*N*64 u64 = 4 MB

    hipMemsetAsync(x2num, 0, zero_bytes, stream);
    maskc_kernel<<<dim3(N_ / 4, B_), 256, 0, stream>>>(adj, mask);
    proj1_kernel<<<dim3(N_ / 8, H_, B_), 256, 0, stream>>>(fea, Wh, wh);
    proj1b_kernel<<<dim3(N_ / 128, H_, B_), 128, 0, stream>>>(wh, ah, wh1, wh2, mkey, whTt);
    attn1_kernel<<<dim3(N_ / 16, S1_, B_), 256, 0, stream>>>(mask, whTt, wh1, wh2, mkey,
                                                             x2num, l1sum);
    proj2_kernel<<<dim3(N_ / 16, B_), 256, 0, stream>>>(x2num, l1sum, Wl, whl2);
    proj2b_kernel<<<dim3(N_ / 128, B_), 128, 0, stream>>>(whl2, al, wh1b, wh2b, mkey + 8, whT2t);
    attn2_kernel<<<dim3(N_ / 16, S2_, B_), 256, 0, stream>>>(mask, whT2t, wh1b, wh2b, mkey + 8,
                                                             outnum, outl);
    finalize2_kernel<<<(B_ * N_ * EN_) / 256, 256, 0, stream>>>(outnum, outl, (float*)d_out);
}

// Round 10
// 327.101 us; speedup vs baseline: 1.0955x; 1.0955x over previous
//
#include <hip/hip_runtime.h>
#include <hip/hip_bf16.h>
#include <stdint.h>

#define B_ 2
#define N_ 4096
#define D_ 128
#define H_ 4
#define HID_ 32
#define EN_ 16
#define ALPHA_ 0.2f
#define S1_ 4
#define S2_ 4
#define LOG2E_ 1.4426950408889634f

typedef __attribute__((ext_vector_type(8))) _Float16 f16x8;
typedef __attribute__((ext_vector_type(4))) float f32x4;
typedef __attribute__((ext_vector_type(8))) unsigned short u16x8;

__device__ __forceinline__ unsigned short f2h(float v) {
    _Float16 h = (_Float16)v;
    return *(unsigned short*)&h;
}

// ---------- adj -> interleaved bitmask. Per 256-j chunk c, word k (k=0..3):
// bit l = (adj[i][c*256 + 4l + k] != 0).  One wave per row, float4 loads.
__global__ __launch_bounds__(256) void maskc_kernel(
    const float* __restrict__ adj, unsigned long long* __restrict__ mask)
{
    const int b = blockIdx.y;
    const int i = blockIdx.x * 4 + (threadIdx.x >> 6);
    const int lane = threadIdx.x & 63;
    const float* ar = adj + ((size_t)b * N_ + i) * N_;
    unsigned long long* mrow = mask + ((size_t)b * N_ + i) * 64;
#pragma unroll 4
    for (int c = 0; c < 16; ++c) {
        float4 v = *(const float4*)(ar + c * 256 + lane * 4);
        unsigned long long b0 = __ballot(v.x != 0.f);
        unsigned long long b1 = __ballot(v.y != 0.f);
        unsigned long long b2 = __ballot(v.z != 0.f);
        unsigned long long b3 = __ballot(v.w != 0.f);
        if (lane == 0) {
            ulonglong2 w01 = {b0, b1}, w23 = {b2, b3};
            *(ulonglong2*)(mrow + c * 4) = w01;
            *(ulonglong2*)(mrow + c * 4 + 2) = w23;
        }
    }
}

// ---------- merged layer-1 projection: per block (8 rows, head h):
// wh1/wh2 (scaled log2e), f16 whTt fragments, per-block max(wh2) -> cmax1.
__global__ __launch_bounds__(256) void proj1_kernel(
    const float* __restrict__ fea, const float* __restrict__ Wh,
    const float* __restrict__ a_heads,
    float* __restrict__ wh1, float* __restrict__ wh2,
    float* __restrict__ cmax1, unsigned short* __restrict__ whTt)
{
    __shared__ float Ws[D_ * HID_];   // 16 KB
    __shared__ float xs[8][D_];       // 4 KB
    __shared__ float as_[2 * HID_];
    __shared__ unsigned short ts[HID_][8];
    __shared__ float rmax[8];
    const int b = blockIdx.z, h = blockIdx.y, i0 = blockIdx.x * 8, tid = threadIdx.x;
    const float* Wp = Wh + h * D_ * HID_;
    for (int idx = tid * 4; idx < D_ * HID_; idx += 1024)
        *(float4*)&Ws[idx] = *(const float4*)(Wp + idx);
    const float* xp = fea + ((size_t)b * N_ + i0) * D_;
    *(float4*)&xs[(tid * 4) >> 7][(tid * 4) & 127] = *(const float4*)(xp + tid * 4);
    if (tid < 2 * HID_) as_[tid] = a_heads[h * 2 * HID_ + tid];
    __syncthreads();
    const int r = tid >> 5, d = tid & 31;
    float acc = 0.f;
#pragma unroll 8
    for (int k = 0; k < D_; ++k) acc += xs[r][k] * Ws[k * HID_ + d];
    ts[d][r] = f2h(acc);                       // V stays unscaled
    float d1 = acc * as_[d], d2 = acc * as_[HID_ + d];
#pragma unroll
    for (int off = 16; off; off >>= 1) {       // reduce over d (32-lane groups)
        d1 += __shfl_xor(d1, off);
        d2 += __shfl_xor(d2, off);
    }
    d1 *= LOG2E_; d2 *= LOG2E_;
    if (d == 0) {
        const size_t o = (size_t)(b * H_ + h) * N_ + i0 + r;
        wh1[o] = d1; wh2[o] = d2; rmax[r] = d2;
    }
    __syncthreads();
    if (tid < HID_) {
        unsigned short* dst = whTt + (size_t)(b * H_ + h) * 131072
                            + (i0 >> 6) * 2048 + tid * 64 + (i0 & 63);
        *(u16x8*)dst = *(u16x8*)&ts[tid][0];
    }
    if (tid == 0) {
        float mx = rmax[0];
#pragma unroll
        for (int k = 1; k < 8; ++k) mx = fmaxf(mx, rmax[k]);
        cmax1[(size_t)(b * H_ + h) * 512 + blockIdx.x] = mx;
    }
}

// ---------- layer-1 fused MFMA attention: bitmask-gated, atomic-free.
// block 256 = 4 waves (one per head), 16 rows, split-K=4, plain-store partials.
__global__ __launch_bounds__(256) void attn1_kernel(
    const unsigned long long* __restrict__ mask, const unsigned short* __restrict__ whT,
    const float* __restrict__ wh1, const float* __restrict__ wh2,
    const float* __restrict__ cmax1,
    float* __restrict__ x2p, float* __restrict__ l1p)
{
    __shared__ unsigned long long mask_s[16][18];   // pad: 2-way (free) banks
    const int b = blockIdx.z, split = blockIdx.y, i0 = blockIdx.x * 16;
    const int tid = threadIdx.x, lane = tid & 63, h = tid >> 6;
    const int m = lane & 15, quad = lane >> 4;
    mask_s[tid >> 4][tid & 15] =
        mask[((size_t)b * N_ + i0 + (tid >> 4)) * 64 + split * 16 + (tid & 15)];
    // exact global max of scaled wh2 from 512 block maxima
    const float* cm = cmax1 + (size_t)(b * H_ + h) * 512;
    float4 c0 = *(const float4*)(cm + lane * 8);
    float4 c1 = *(const float4*)(cm + lane * 8 + 4);
    float Mh = fmaxf(fmaxf(fmaxf(c0.x, c0.y), fmaxf(c0.z, c0.w)),
                     fmaxf(fmaxf(c1.x, c1.y), fmaxf(c1.z, c1.w)));
#pragma unroll
    for (int off = 32; off; off >>= 1) Mh = fmaxf(Mh, __shfl_xor(Mh, off));
    const float w1r = wh1[(size_t)(b * H_ + h) * N_ + i0 + m];
    const float sbound = w1r + Mh;
    const float mr = fmaxf(sbound, ALPHA_ * sbound);   // lrelu = max(s, 0.2s)
    const float* w2h = wh2 + (size_t)(b * H_ + h) * N_;
    const unsigned short* whTp = whT + (size_t)(b * H_ + h) * 131072;
    f32x4 acc0 = {0.f, 0.f, 0.f, 0.f}, acc1 = {0.f, 0.f, 0.f, 0.f};
    f32x4 acc2 = {0.f, 0.f, 0.f, 0.f};
    f16x8 ones;
#pragma unroll
    for (int q = 0; q < 8; ++q) ones[q] = (_Float16)1.0f;
    const int jt0 = split * (N_ / S1_);
    __syncthreads();                                 // mask_s ready; no barriers after

    for (int c = 0; c < 4; ++c) {                    // 4 chunks of 256 j
        unsigned long long W0 = mask_s[m][c * 4 + 0], W1 = mask_s[m][c * 4 + 1];
        unsigned long long W2 = mask_s[m][c * 4 + 2], W3 = mask_s[m][c * 4 + 3];
#pragma unroll
        for (int q4 = 0; q4 < 4; ++q4) {             // 4 tiles of 64 j
            const int t = c * 4 + q4;
            const int jt = jt0 + t * 64;
            const int jb = split * 16 + t;
#pragma unroll
            for (int ks = 0; ks < 2; ++ks) {
                const int ko = ks * 32 + quad * 8;
                const int sh = 16 * q4 + 8 * ks + 2 * quad;
                unsigned int g0 = (unsigned int)(W0 >> sh) & 3u;
                unsigned int g1 = (unsigned int)(W1 >> sh) & 3u;
                unsigned int g2 = (unsigned int)(W2 >> sh) & 3u;
                unsigned int g3 = (unsigned int)(W3 >> sh) & 3u;
                float wv8[8];
                *(float4*)&wv8[0] = *(const float4*)(w2h + jt + ko);
                *(float4*)&wv8[4] = *(const float4*)(w2h + jt + ko + 4);
                f16x8 af;
#pragma unroll
                for (int q = 0; q < 4; ++q) {
                    float p2[2];
#pragma unroll
                    for (int cc = 0; cc < 2; ++cc) {
                        const int jj = q * 2 + cc;
                        unsigned int gw = (jj & 3) == 0 ? g0 : (jj & 3) == 1 ? g1
                                        : (jj & 3) == 2 ? g2 : g3;
                        unsigned int bit = gw & (1u << (jj >> 2));
                        float s = w1r + wv8[jj];
                        float e = fmaxf(s, ALPHA_ * s);
                        float tt = (bit == 0u || s == 0.f) ? -1e38f : (e - mr);
                        p2[cc] = __builtin_amdgcn_exp2f(tt);
                    }
                    auto pr = __builtin_amdgcn_cvt_pkrtz(p2[0], p2[1]);
                    af[q * 2] = (_Float16)pr[0]; af[q * 2 + 1] = (_Float16)pr[1];
                }
                const unsigned short* bp = whTp + (size_t)jb * 2048 + m * 64 + ko;
                f16x8 b0 = *(const f16x8*)bp;
                f16x8 b1 = *(const f16x8*)(bp + 1024);
                acc0 = __builtin_amdgcn_mfma_f32_16x16x32_f16(af, b0, acc0, 0, 0, 0);
                acc1 = __builtin_amdgcn_mfma_f32_16x16x32_f16(af, b1, acc1, 0, 0, 0);
                acc2 = __builtin_amdgcn_mfma_f32_16x16x32_f16(af, ones, acc2, 0, 0, 0);
            }
        }
    }
    // plain-store split partials (no atomics)
    float* xp = x2p + (((size_t)split * B_ + b) * N_ + i0) * D_ + h * HID_;
#pragma unroll
    for (int reg = 0; reg < 4; ++reg) {
        const int row = quad * 4 + reg;              // C/D: col=lane&15, row=quad*4+reg
        xp[(size_t)row * D_ + m] = acc0[reg];
        xp[(size_t)row * D_ + 16 + m] = acc1[reg];
    }
    if (m == 0) {
#pragma unroll
        for (int reg = 0; reg < 4; ++reg)
            l1p[(((size_t)split * B_ + b) * N_ + i0 + quad * 4 + reg) * H_ + h] = acc2[reg];
    }
}

// ---------- merged layer-2 projection: sum split partials, finalize layer-1
// (div + ELU), @ W_last; emit wh1b/wh2b (scaled), whT2t f16, cmax2.
__global__ __launch_bounds__(256) void proj2_kernel(
    const float* __restrict__ x2p, const float* __restrict__ l1p,
    const float* __restrict__ Wl, const float* __restrict__ a_last,
    float* __restrict__ wh1b, float* __restrict__ wh2b,
    float* __restrict__ cmax2, unsigned short* __restrict__ whT2t)
{
    __shared__ float Ws[D_ * EN_];
    __shared__ float xs[16][D_];
    __shared__ float as_[2 * EN_];
    __shared__ unsigned short ts[EN_][16];
    __shared__ float rmax[16];
    const int b = blockIdx.y, i0 = blockIdx.x * 16, tid = threadIdx.x;
    for (int idx = tid * 4; idx < D_ * EN_; idx += 1024)
        *(float4*)&Ws[idx] = *(const float4*)(Wl + idx);
    if (tid < 2 * EN_) as_[tid] = a_last[tid];
    for (int idx = tid * 4; idx < 16 * D_; idx += 1024) {
        const int r = idx >> 7, hd = idx & 127, h = hd >> 5;
        float4 v = {0.f, 0.f, 0.f, 0.f};
        float l = 0.f;
#pragma unroll
        for (int s = 0; s < S1_; ++s) {
            const size_t gi = ((size_t)s * B_ + b) * N_ + i0 + r;
            float4 p = *(const float4*)(x2p + gi * D_ + hd);
            v.x += p.x; v.y += p.y; v.z += p.z; v.w += p.w;
            l += l1p[gi * H_ + h];
        }
        float linv = 1.f / fmaxf(l, 1e-30f);
        float o0 = v.x * linv, o1 = v.y * linv, o2 = v.z * linv, o3 = v.w * linv;
        xs[r][hd]     = o0 > 0.f ? o0 : expm1f(o0);
        xs[r][hd + 1] = o1 > 0.f ? o1 : expm1f(o1);
        xs[r][hd + 2] = o2 > 0.f ? o2 : expm1f(o2);
        xs[r][hd + 3] = o3 > 0.f ? o3 : expm1f(o3);
    }
    __syncthreads();
    const int r = tid >> 4, e = tid & 15;
    float acc = 0.f;
#pragma unroll 8
    for (int k = 0; k < D_; ++k) acc += xs[r][k] * Ws[k * EN_ + e];
    ts[e][r] = f2h(acc);
    float d1 = acc * as_[e], d2 = acc * as_[EN_ + e];
#pragma unroll
    for (int off = 8; off; off >>= 1) {              // reduce over e (16-lane groups)
        d1 += __shfl_xor(d1, off);
        d2 += __shfl_xor(d2, off);
    }
    d1 *= LOG2E_; d2 *= LOG2E_;
    if (e == 0) {
        wh1b[(size_t)b * N_ + i0 + r] = d1;
        wh2b[(size_t)b * N_ + i0 + r] = d2;
        rmax[r] = d2;
    }
    __syncthreads();
    if (tid < EN_) {
        unsigned short* dst = whT2t + (size_t)b * 65536
                            + (i0 >> 6) * 1024 + tid * 64 + (i0 & 63);
        *(u16x8*)dst = *(u16x8*)&ts[tid][0];
        *(u16x8*)(dst + 8) = *(u16x8*)&ts[tid][8];
    }
    if (tid == 0) {
        float mx = rmax[0];
#pragma unroll
        for (int k = 1; k < 16; ++k) mx = fmaxf(mx, rmax[k]);
        cmax2[(size_t)b * 256 + blockIdx.x] = mx;
    }
}

// ---------- layer-2 fused MFMA attention: bitmask-gated, atomic-free.
// 4 waves each cover one 256-j chunk of the split; LDS combine; partial stores.
__global__ __launch_bounds__(256) void attn2_kernel(
    const unsigned long long* __restrict__ mask, const unsigned short* __restrict__ whT2,
    const float* __restrict__ wh1b, const float* __restrict__ wh2b,
    const float* __restrict__ cmax2,
    float* __restrict__ outp, float* __restrict__ outlp)
{
    __shared__ unsigned long long mask_s[16][18];
    __shared__ float accred[4][16][17];
    __shared__ float lred[4][16];
    const int b = blockIdx.z, split = blockIdx.y, i0 = blockIdx.x * 16;
    const int tid = threadIdx.x, lane = tid & 63, wv = tid >> 6;
    const int m = lane & 15, quad = lane >> 4;
    mask_s[tid >> 4][tid & 15] =
        mask[((size_t)b * N_ + i0 + (tid >> 4)) * 64 + split * 16 + (tid & 15)];
    const float* cm = cmax2 + (size_t)b * 256;
    float4 c0 = *(const float4*)(cm + lane * 4);
    float Mh = fmaxf(fmaxf(c0.x, c0.y), fmaxf(c0.z, c0.w));
#pragma unroll
    for (int off = 32; off; off >>= 1) Mh = fmaxf(Mh, __shfl_xor(Mh, off));
    const float w1r = wh1b[(size_t)b * N_ + i0 + m];
    const float sbound = w1r + Mh;
    const float mr = fmaxf(sbound, ALPHA_ * sbound);
    const float* w2g = wh2b + (size_t)b * N_;
    const unsigned short* wTg = whT2 + (size_t)b * 65536;
    f32x4 acc = {0.f, 0.f, 0.f, 0.f}, acc2 = {0.f, 0.f, 0.f, 0.f};
    f16x8 ones;
#pragma unroll
    for (int q = 0; q < 8; ++q) ones[q] = (_Float16)1.0f;
    const int jt0 = split * (N_ / S2_);
    __syncthreads();
    unsigned long long W0 = mask_s[m][wv * 4 + 0], W1 = mask_s[m][wv * 4 + 1];
    unsigned long long W2 = mask_s[m][wv * 4 + 2], W3 = mask_s[m][wv * 4 + 3];
#pragma unroll
    for (int q4 = 0; q4 < 4; ++q4) {                 // wave's chunk = wv; 4 tiles
        const int t = wv * 4 + q4;
        const int jt = jt0 + t * 64;
        const int jb = split * 16 + t;
#pragma unroll
        for (int ks = 0; ks < 2; ++ks) {
            const int ko = ks * 32 + quad * 8;
            const int sh = 16 * q4 + 8 * ks + 2 * quad;
            unsigned int g0 = (unsigned int)(W0 >> sh) & 3u;
            unsigned int g1 = (unsigned int)(W1 >> sh) & 3u;
            unsigned int g2 = (unsigned int)(W2 >> sh) & 3u;
            unsigned int g3 = (unsigned int)(W3 >> sh) & 3u;
            float wv8[8];
            *(float4*)&wv8[0] = *(const float4*)(w2g + jt + ko);
            *(float4*)&wv8[4] = *(const float4*)(w2g + jt + ko + 4);
            f16x8 af;
#pragma unroll
            for (int q = 0; q < 4; ++q) {
                float p2[2];
#pragma unroll
                for (int cc = 0; cc < 2; ++cc) {
                    const int jj = q * 2 + cc;
                    unsigned int gw = (jj & 3) == 0 ? g0 : (jj & 3) == 1 ? g1
                                    : (jj & 3) == 2 ? g2 : g3;
                    unsigned int bit = gw & (1u << (jj >> 2));
                    float s = w1r + wv8[jj];
                    float e = fmaxf(s, ALPHA_ * s);
                    float tt = (bit == 0u || s == 0.f) ? -1e38f : (e - mr);
                    p2[cc] = __builtin_amdgcn_exp2f(tt);
                }
                auto pr = __builtin_amdgcn_cvt_pkrtz(p2[0], p2[1]);
                af[q * 2] = (_Float16)pr[0]; af[q * 2 + 1] = (_Float16)pr[1];
            }
            f16x8 b0 = *(const f16x8*)(wTg + (size_t)jb * 1024 + m * 64 + ko);
            acc = __builtin_amdgcn_mfma_f32_16x16x32_f16(af, b0, acc, 0, 0, 0);
            acc2 = __builtin_amdgcn_mfma_f32_16x16x32_f16(af, ones, acc2, 0, 0, 0);
        }
    }
#pragma unroll
    for (int reg = 0; reg < 4; ++reg)
        accred[wv][quad * 4 + reg][m] = acc[reg];
    if (m == 0) {
#pragma unroll
        for (int reg = 0; reg < 4; ++reg) lred[wv][quad * 4 + reg] = acc2[reg];
    }
    __syncthreads();
    const int row = tid >> 4, col = tid & 15;
    float s = accred[0][row][col] + accred[1][row][col]
            + accred[2][row][col] + accred[3][row][col];
    outp[(((size_t)split * B_ + b) * N_ + i0 + row) * EN_ + col] = s;
    if (tid < 16) {
        float l = lred[0][tid] + lred[1][tid] + lred[2][tid] + lred[3][tid];
        outlp[((size_t)split * B_ + b) * N_ + i0 + tid] = l;
    }
}

// ---------- final: sum split partials, divide, ELU
__global__ __launch_bounds__(256) void finalize2_kernel(
    const float* __restrict__ outp, const float* __restrict__ outlp,
    float* __restrict__ out)
{
    const int id = blockIdx.x * 256 + threadIdx.x;      // B*N*EN
    const int gi = id >> 4;
    float num = 0.f, l = 0.f;
#pragma unroll
    for (int s = 0; s < S2_; ++s) {
        num += outp[(size_t)s * B_ * N_ * EN_ + id];
        l   += outlp[(size_t)s * B_ * N_ + gi];
    }
    float v = num / fmaxf(l, 1e-30f);
    out[id] = v > 0.f ? v : expm1f(v);
}

extern "C" void kernel_launch(void* const* d_in, const int* in_sizes, int n_in,
                              void* d_out, int out_size, void* d_ws, size_t ws_size,
                              hipStream_t stream)
{
    const float* fea = (const float*)d_in[0];
    const float* adj = (const float*)d_in[1];
    const float* Wh  = (const float*)d_in[2];
    const float* ah  = (const float*)d_in[3];
    const float* Wl  = (const float*)d_in[4];
    const float* al  = (const float*)d_in[5];

    float* p = (float*)d_ws;
    float* wh1   = p;  p += (size_t)B_ * H_ * N_;            // 32768
    float* wh2   = p;  p += (size_t)B_ * H_ * N_;            // 32768
    float* wh1b  = p;  p += (size_t)B_ * N_;                 // 8192
    float* wh2b  = p;  p += (size_t)B_ * N_;                 // 8192
    float* cmax1 = p;  p += (size_t)B_ * H_ * 512;           // 4096
    float* cmax2 = p;  p += (size_t)B_ * 256;                // 512
    float* l1p   = p;  p += (size_t)S1_ * B_ * N_ * H_;      // 131072
    float* x2p   = p;  p += (size_t)S1_ * B_ * N_ * D_;      // 4194304
    float* outp  = p;  p += (size_t)S2_ * B_ * N_ * EN_;     // 524288
    float* outlp = p;  p += (size_t)S2_ * B_ * N_;           // 32768
    unsigned long long* mask = (unsigned long long*)p;       // B*N*64 u64 = 4 MB
    unsigned short* whTt  = (unsigned short*)(mask + (size_t)B_ * N_ * 64);  // 2 MB
    unsigned short* whT2t = whTt + (size_t)B_ * H_ * 131072;                 // 256 KB

    maskc_kernel<<<dim3(N_ / 4, B_), 256, 0, stream>>>(adj, mask);
    proj1_kernel<<<dim3(N_ / 8, H_, B_), 256, 0, stream>>>(fea, Wh, ah,
                                                           wh1, wh2, cmax1, whTt);
    attn1_kernel<<<dim3(N_ / 16, S1_, B_), 256, 0, stream>>>(mask, whTt, wh1, wh2, cmax1,
                                                             x2p, l1p);
    proj2_kernel<<<dim3(N_ / 16, B_), 256, 0, stream>>>(x2p, l1p, Wl, al,
                                                        wh1b, wh2b, cmax2, whT2t);
    attn2_kernel<<<dim3(N_ / 16, S2_, B_), 256, 0, stream>>>(mask, whT2t, wh1b, wh2b, cmax2,
                                                             outp, outlp);
    finalize2_kernel<<<(B_ * N_ * EN_) / 256, 256, 0, stream>>>(outp, outlp, (float*)d_out);
}

// Round 11
// 320.565 us; speedup vs baseline: 1.1178x; 1.0204x over previous
//
#include <hip/hip_runtime.h>
#include <hip/hip_bf16.h>
#include <stdint.h>

#define B_ 2
#define N_ 4096
#define D_ 128
#define H_ 4
#define HID_ 32
#define EN_ 16
#define ALPHA_ 0.2f
#define S1_ 4
#define S2_ 4
#define LOG2E_ 1.4426950408889634f

typedef __attribute__((ext_vector_type(8))) _Float16 f16x8;
typedef __attribute__((ext_vector_type(4))) float f32x4;
typedef __attribute__((ext_vector_type(8))) unsigned short u16x8;

__device__ __forceinline__ unsigned short f2h(float v) {
    _Float16 h = (_Float16)v;
    return *(unsigned short*)&h;
}

// ---------- adj -> interleaved bitmask. Per 256-j chunk c, word k (k=0..3):
// bit l = (adj[i][c*256 + 4l + k] != 0).  One wave per row, float4 loads.
__global__ __launch_bounds__(256) void maskc_kernel(
    const float* __restrict__ adj, unsigned long long* __restrict__ mask)
{
    const int b = blockIdx.y;
    const int i = blockIdx.x * 4 + (threadIdx.x >> 6);
    const int lane = threadIdx.x & 63;
    const float* ar = adj + ((size_t)b * N_ + i) * N_;
    unsigned long long* mrow = mask + ((size_t)b * N_ + i) * 64;
#pragma unroll 4
    for (int c = 0; c < 16; ++c) {
        float4 v = *(const float4*)(ar + c * 256 + lane * 4);
        unsigned long long b0 = __ballot(v.x != 0.f);
        unsigned long long b1 = __ballot(v.y != 0.f);
        unsigned long long b2 = __ballot(v.z != 0.f);
        unsigned long long b3 = __ballot(v.w != 0.f);
        if (lane == 0) {
            ulonglong2 w01 = {b0, b1}, w23 = {b2, b3};
            *(ulonglong2*)(mrow + c * 4) = w01;
            *(ulonglong2*)(mrow + c * 4 + 2) = w23;
        }
    }
}

// ---------- merged layer-1 projection (unchanged from R10)
__global__ __launch_bounds__(256) void proj1_kernel(
    const float* __restrict__ fea, const float* __restrict__ Wh,
    const float* __restrict__ a_heads,
    float* __restrict__ wh1, float* __restrict__ wh2,
    float* __restrict__ cmax1, unsigned short* __restrict__ whTt)
{
    __shared__ float Ws[D_ * HID_];
    __shared__ float xs[8][D_];
    __shared__ float as_[2 * HID_];
    __shared__ unsigned short ts[HID_][8];
    __shared__ float rmax[8];
    const int b = blockIdx.z, h = blockIdx.y, i0 = blockIdx.x * 8, tid = threadIdx.x;
    const float* Wp = Wh + h * D_ * HID_;
    for (int idx = tid * 4; idx < D_ * HID_; idx += 1024)
        *(float4*)&Ws[idx] = *(const float4*)(Wp + idx);
    const float* xp = fea + ((size_t)b * N_ + i0) * D_;
    *(float4*)&xs[(tid * 4) >> 7][(tid * 4) & 127] = *(const float4*)(xp + tid * 4);
    if (tid < 2 * HID_) as_[tid] = a_heads[h * 2 * HID_ + tid];
    __syncthreads();
    const int r = tid >> 5, d = tid & 31;
    float acc = 0.f;
#pragma unroll 8
    for (int k = 0; k < D_; ++k) acc += xs[r][k] * Ws[k * HID_ + d];
    ts[d][r] = f2h(acc);
    float d1 = acc * as_[d], d2 = acc * as_[HID_ + d];
#pragma unroll
    for (int off = 16; off; off >>= 1) {
        d1 += __shfl_xor(d1, off);
        d2 += __shfl_xor(d2, off);
    }
    d1 *= LOG2E_; d2 *= LOG2E_;
    if (d == 0) {
        const size_t o = (size_t)(b * H_ + h) * N_ + i0 + r;
        wh1[o] = d1; wh2[o] = d2; rmax[r] = d2;
    }
    __syncthreads();
    if (tid < HID_) {
        unsigned short* dst = whTt + (size_t)(b * H_ + h) * 131072
                            + (i0 >> 6) * 2048 + tid * 64 + (i0 & 63);
        *(u16x8*)dst = *(u16x8*)&ts[tid][0];
    }
    if (tid == 0) {
        float mx = rmax[0];
#pragma unroll
        for (int k = 1; k < 8; ++k) mx = fmaxf(mx, rmax[k]);
        cmax1[(size_t)(b * H_ + h) * 512 + blockIdx.x] = mx;
    }
}

// ---------- layer-1 fused MFMA attention: bitmask-gated, register-pipelined.
// block 256 = 4 waves (one per head), 16 rows, split-K=4, plain-store partials.
// Tile t+1's whT fragments + w2 loaded into "next" regs while computing tile t.
__global__ __launch_bounds__(256) void attn1_kernel(
    const unsigned long long* __restrict__ mask, const unsigned short* __restrict__ whT,
    const float* __restrict__ wh1, const float* __restrict__ wh2,
    const float* __restrict__ cmax1,
    float* __restrict__ x2p, float* __restrict__ l1p)
{
    __shared__ unsigned long long mask_s[16][18];
    const int b = blockIdx.z, split = blockIdx.y, i0 = blockIdx.x * 16;
    const int tid = threadIdx.x, lane = tid & 63, h = tid >> 6;
    const int m = lane & 15, quad = lane >> 4;
    mask_s[tid >> 4][tid & 15] =
        mask[((size_t)b * N_ + i0 + (tid >> 4)) * 64 + split * 16 + (tid & 15)];
    const float* cm = cmax1 + (size_t)(b * H_ + h) * 512;
    float4 c0 = *(const float4*)(cm + lane * 8);
    float4 c1 = *(const float4*)(cm + lane * 8 + 4);
    float Mh = fmaxf(fmaxf(fmaxf(c0.x, c0.y), fmaxf(c0.z, c0.w)),
                     fmaxf(fmaxf(c1.x, c1.y), fmaxf(c1.z, c1.w)));
#pragma unroll
    for (int off = 32; off; off >>= 1) Mh = fmaxf(Mh, __shfl_xor(Mh, off));
    const float w1r = wh1[(size_t)(b * H_ + h) * N_ + i0 + m];
    const float sbound = w1r + Mh;
    const float mr = fmaxf(sbound, ALPHA_ * sbound);
    const float* w2h = wh2 + (size_t)(b * H_ + h) * N_;
    const unsigned short* whTp = whT + (size_t)(b * H_ + h) * 131072;
    f32x4 acc0 = {0.f, 0.f, 0.f, 0.f}, acc1 = {0.f, 0.f, 0.f, 0.f};
    f32x4 acc2 = {0.f, 0.f, 0.f, 0.f};
    f16x8 ones;
#pragma unroll
    for (int q = 0; q < 8; ++q) ones[q] = (_Float16)1.0f;
    const int jt0 = split * (N_ / S1_);
    __syncthreads();

    // tile-invariant lane base pointers
    const unsigned short* bpb = whTp + (size_t)split * 16 * 2048 + m * 64 + quad * 8;
    const float* wvb = w2h + jt0 + quad * 8;
    // current-tile registers (prologue: tile 0)
    f16x8 cb00 = *(const f16x8*)(bpb);
    f16x8 cb10 = *(const f16x8*)(bpb + 32);
    f16x8 cb01 = *(const f16x8*)(bpb + 1024);
    f16x8 cb11 = *(const f16x8*)(bpb + 1056);
    float4 cu0 = *(const float4*)(wvb);
    float4 cu1 = *(const float4*)(wvb + 4);
    float4 cv0 = *(const float4*)(wvb + 32);
    float4 cv1 = *(const float4*)(wvb + 36);

    int t = 0;
    for (int c = 0; c < 4; ++c) {
        unsigned long long A0 = mask_s[m][c * 4 + 0], A1 = mask_s[m][c * 4 + 1];
        unsigned long long A2 = mask_s[m][c * 4 + 2], A3 = mask_s[m][c * 4 + 3];
#pragma unroll
        for (int q4 = 0; q4 < 4; ++q4) {
            // prefetch tile t+1 (overrun at t=15 lands in adjacent ws; unused)
            const unsigned short* np = bpb + (size_t)(t + 1) * 2048;
            const float* nw = wvb + (t + 1) * 64;
            f16x8 nb00 = *(const f16x8*)(np);
            f16x8 nb10 = *(const f16x8*)(np + 32);
            f16x8 nb01 = *(const f16x8*)(np + 1024);
            f16x8 nb11 = *(const f16x8*)(np + 1056);
            float4 nu0 = *(const float4*)(nw);
            float4 nu1 = *(const float4*)(nw + 4);
            float4 nv0 = *(const float4*)(nw + 32);
            float4 nv1 = *(const float4*)(nw + 36);
            // compute tile t from current regs
#pragma unroll
            for (int ks = 0; ks < 2; ++ks) {
                const int sh = 16 * q4 + 8 * ks + 2 * quad;
                unsigned int g0 = (unsigned int)(A0 >> sh) & 3u;
                unsigned int g1 = (unsigned int)(A1 >> sh) & 3u;
                unsigned int g2 = (unsigned int)(A2 >> sh) & 3u;
                unsigned int g3 = (unsigned int)(A3 >> sh) & 3u;
                float wv8[8];
                if (ks == 0) { *(float4*)&wv8[0] = cu0; *(float4*)&wv8[4] = cu1; }
                else         { *(float4*)&wv8[0] = cv0; *(float4*)&wv8[4] = cv1; }
                f16x8 af;
#pragma unroll
                for (int q = 0; q < 4; ++q) {
                    float p2[2];
#pragma unroll
                    for (int cc = 0; cc < 2; ++cc) {
                        const int jj = q * 2 + cc;
                        unsigned int gw = (jj & 3) == 0 ? g0 : (jj & 3) == 1 ? g1
                                        : (jj & 3) == 2 ? g2 : g3;
                        unsigned int bit = gw & (1u << (jj >> 2));
                        float s = w1r + wv8[jj];
                        float e = fmaxf(s, ALPHA_ * s);
                        float tt = (bit == 0u || s == 0.f) ? -1e38f : (e - mr);
                        p2[cc] = __builtin_amdgcn_exp2f(tt);
                    }
                    auto pr = __builtin_amdgcn_cvt_pkrtz(p2[0], p2[1]);
                    af[q * 2] = (_Float16)pr[0]; af[q * 2 + 1] = (_Float16)pr[1];
                }
                f16x8 bb0 = ks ? cb10 : cb00;
                f16x8 bb1 = ks ? cb11 : cb01;
                acc0 = __builtin_amdgcn_mfma_f32_16x16x32_f16(af, bb0, acc0, 0, 0, 0);
                acc1 = __builtin_amdgcn_mfma_f32_16x16x32_f16(af, bb1, acc1, 0, 0, 0);
                acc2 = __builtin_amdgcn_mfma_f32_16x16x32_f16(af, ones, acc2, 0, 0, 0);
            }
            // rotate
            cb00 = nb00; cb10 = nb10; cb01 = nb01; cb11 = nb11;
            cu0 = nu0; cu1 = nu1; cv0 = nv0; cv1 = nv1;
            ++t;
        }
    }
    float* xp = x2p + (((size_t)split * B_ + b) * N_ + i0) * D_ + h * HID_;
#pragma unroll
    for (int reg = 0; reg < 4; ++reg) {
        const int row = quad * 4 + reg;              // C/D: col=lane&15, row=quad*4+reg
        xp[(size_t)row * D_ + m] = acc0[reg];
        xp[(size_t)row * D_ + 16 + m] = acc1[reg];
    }
    if (m == 0) {
#pragma unroll
        for (int reg = 0; reg < 4; ++reg)
            l1p[(((size_t)split * B_ + b) * N_ + i0 + quad * 4 + reg) * H_ + h] = acc2[reg];
    }
}

// ---------- merged layer-2 projection (unchanged from R10)
__global__ __launch_bounds__(256) void proj2_kernel(
    const float* __restrict__ x2p, const float* __restrict__ l1p,
    const float* __restrict__ Wl, const float* __restrict__ a_last,
    float* __restrict__ wh1b, float* __restrict__ wh2b,
    float* __restrict__ cmax2, unsigned short* __restrict__ whT2t)
{
    __shared__ float Ws[D_ * EN_];
    __shared__ float xs[16][D_];
    __shared__ float as_[2 * EN_];
    __shared__ unsigned short ts[EN_][16];
    __shared__ float rmax[16];
    const int b = blockIdx.y, i0 = blockIdx.x * 16, tid = threadIdx.x;
    for (int idx = tid * 4; idx < D_ * EN_; idx += 1024)
        *(float4*)&Ws[idx] = *(const float4*)(Wl + idx);
    if (tid < 2 * EN_) as_[tid] = a_last[tid];
    for (int idx = tid * 4; idx < 16 * D_; idx += 1024) {
        const int r = idx >> 7, hd = idx & 127, h = hd >> 5;
        float4 v = {0.f, 0.f, 0.f, 0.f};
        float l = 0.f;
#pragma unroll
        for (int s = 0; s < S1_; ++s) {
            const size_t gi = ((size_t)s * B_ + b) * N_ + i0 + r;
            float4 p = *(const float4*)(x2p + gi * D_ + hd);
            v.x += p.x; v.y += p.y; v.z += p.z; v.w += p.w;
            l += l1p[gi * H_ + h];
        }
        float linv = 1.f / fmaxf(l, 1e-30f);
        float o0 = v.x * linv, o1 = v.y * linv, o2 = v.z * linv, o3 = v.w * linv;
        xs[r][hd]     = o0 > 0.f ? o0 : expm1f(o0);
        xs[r][hd + 1] = o1 > 0.f ? o1 : expm1f(o1);
        xs[r][hd + 2] = o2 > 0.f ? o2 : expm1f(o2);
        xs[r][hd + 3] = o3 > 0.f ? o3 : expm1f(o3);
    }
    __syncthreads();
    const int r = tid >> 4, e = tid & 15;
    float acc = 0.f;
#pragma unroll 8
    for (int k = 0; k < D_; ++k) acc += xs[r][k] * Ws[k * EN_ + e];
    ts[e][r] = f2h(acc);
    float d1 = acc * as_[e], d2 = acc * as_[EN_ + e];
#pragma unroll
    for (int off = 8; off; off >>= 1) {
        d1 += __shfl_xor(d1, off);
        d2 += __shfl_xor(d2, off);
    }
    d1 *= LOG2E_; d2 *= LOG2E_;
    if (e == 0) {
        wh1b[(size_t)b * N_ + i0 + r] = d1;
        wh2b[(size_t)b * N_ + i0 + r] = d2;
        rmax[r] = d2;
    }
    __syncthreads();
    if (tid < EN_) {
        unsigned short* dst = whT2t + (size_t)b * 65536
                            + (i0 >> 6) * 1024 + tid * 64 + (i0 & 63);
        *(u16x8*)dst = *(u16x8*)&ts[tid][0];
        *(u16x8*)(dst + 8) = *(u16x8*)&ts[tid][8];
    }
    if (tid == 0) {
        float mx = rmax[0];
#pragma unroll
        for (int k = 1; k < 16; ++k) mx = fmaxf(mx, rmax[k]);
        cmax2[(size_t)b * 256 + blockIdx.x] = mx;
    }
}

// ---------- layer-2 fused MFMA attention: bitmask-gated, register-pipelined.
__global__ __launch_bounds__(256) void attn2_kernel(
    const unsigned long long* __restrict__ mask, const unsigned short* __restrict__ whT2,
    const float* __restrict__ wh1b, const float* __restrict__ wh2b,
    const float* __restrict__ cmax2,
    float* __restrict__ outp, float* __restrict__ outlp)
{
    __shared__ unsigned long long mask_s[16][18];
    __shared__ float accred[4][16][17];
    __shared__ float lred[4][16];
    const int b = blockIdx.z, split = blockIdx.y, i0 = blockIdx.x * 16;
    const int tid = threadIdx.x, lane = tid & 63, wv = tid >> 6;
    const int m = lane & 15, quad = lane >> 4;
    mask_s[tid >> 4][tid & 15] =
        mask[((size_t)b * N_ + i0 + (tid >> 4)) * 64 + split * 16 + (tid & 15)];
    const float* cm = cmax2 + (size_t)b * 256;
    float4 c0 = *(const float4*)(cm + lane * 4);
    float Mh = fmaxf(fmaxf(c0.x, c0.y), fmaxf(c0.z, c0.w));
#pragma unroll
    for (int off = 32; off; off >>= 1) Mh = fmaxf(Mh, __shfl_xor(Mh, off));
    const float w1r = wh1b[(size_t)b * N_ + i0 + m];
    const float sbound = w1r + Mh;
    const float mr = fmaxf(sbound, ALPHA_ * sbound);
    const float* w2g = wh2b + (size_t)b * N_;
    const unsigned short* wTg = whT2 + (size_t)b * 65536;
    f32x4 acc = {0.f, 0.f, 0.f, 0.f}, acc2 = {0.f, 0.f, 0.f, 0.f};
    f16x8 ones;
#pragma unroll
    for (int q = 0; q < 8; ++q) ones[q] = (_Float16)1.0f;
    const int jt0 = split * (N_ / S2_);
    __syncthreads();
    unsigned long long W0 = mask_s[m][wv * 4 + 0], W1 = mask_s[m][wv * 4 + 1];
    unsigned long long W2 = mask_s[m][wv * 4 + 2], W3 = mask_s[m][wv * 4 + 3];

    const unsigned short* wTb = wTg + (size_t)(split * 16 + wv * 4) * 1024 + m * 64 + quad * 8;
    const float* wvb = w2g + jt0 + wv * 256 + quad * 8;
    f16x8 cb0 = *(const f16x8*)(wTb);
    f16x8 cb1 = *(const f16x8*)(wTb + 32);
    float4 cu0 = *(const float4*)(wvb);
    float4 cu1 = *(const float4*)(wvb + 4);
    float4 cv0 = *(const float4*)(wvb + 32);
    float4 cv1 = *(const float4*)(wvb + 36);
#pragma unroll
    for (int q4 = 0; q4 < 4; ++q4) {
        const unsigned short* np = wTb + (size_t)(q4 + 1) * 1024;
        const float* nw = wvb + (q4 + 1) * 64;
        f16x8 nb0 = *(const f16x8*)(np);
        f16x8 nb1 = *(const f16x8*)(np + 32);
        float4 nu0 = *(const float4*)(nw);
        float4 nu1 = *(const float4*)(nw + 4);
        float4 nv0 = *(const float4*)(nw + 32);
        float4 nv1 = *(const float4*)(nw + 36);
#pragma unroll
        for (int ks = 0; ks < 2; ++ks) {
            const int sh = 16 * q4 + 8 * ks + 2 * quad;
            unsigned int g0 = (unsigned int)(W0 >> sh) & 3u;
            unsigned int g1 = (unsigned int)(W1 >> sh) & 3u;
            unsigned int g2 = (unsigned int)(W2 >> sh) & 3u;
            unsigned int g3 = (unsigned int)(W3 >> sh) & 3u;
            float wv8[8];
            if (ks == 0) { *(float4*)&wv8[0] = cu0; *(float4*)&wv8[4] = cu1; }
            else         { *(float4*)&wv8[0] = cv0; *(float4*)&wv8[4] = cv1; }
            f16x8 af;
#pragma unroll
            for (int q = 0; q < 4; ++q) {
                float p2[2];
#pragma unroll
                for (int cc = 0; cc < 2; ++cc) {
                    const int jj = q * 2 + cc;
                    unsigned int gw = (jj & 3) == 0 ? g0 : (jj & 3) == 1 ? g1
                                    : (jj & 3) == 2 ? g2 : g3;
                    unsigned int bit = gw & (1u << (jj >> 2));
                    float s = w1r + wv8[jj];
                    float e = fmaxf(s, ALPHA_ * s);
                    float tt = (bit == 0u || s == 0.f) ? -1e38f : (e - mr);
                    p2[cc] = __builtin_amdgcn_exp2f(tt);
                }
                auto pr = __builtin_amdgcn_cvt_pkrtz(p2[0], p2[1]);
                af[q * 2] = (_Float16)pr[0]; af[q * 2 + 1] = (_Float16)pr[1];
            }
            f16x8 bb0 = ks ? cb1 : cb0;
            acc = __builtin_amdgcn_mfma_f32_16x16x32_f16(af, bb0, acc, 0, 0, 0);
            acc2 = __builtin_amdgcn_mfma_f32_16x16x32_f16(af, ones, acc2, 0, 0, 0);
        }
        cb0 = nb0; cb1 = nb1;
        cu0 = nu0; cu1 = nu1; cv0 = nv0; cv1 = nv1;
    }
#pragma unroll
    for (int reg = 0; reg < 4; ++reg)
        accred[wv][quad * 4 + reg][m] = acc[reg];
    if (m == 0) {
#pragma unroll
        for (int reg = 0; reg < 4; ++reg) lred[wv][quad * 4 + reg] = acc2[reg];
    }
    __syncthreads();
    const int row = tid >> 4, col = tid & 15;
    float s = accred[0][row][col] + accred[1][row][col]
            + accred[2][row][col] + accred[3][row][col];
    outp[(((size_t)split * B_ + b) * N_ + i0 + row) * EN_ + col] = s;
    if (tid < 16) {
        float l = lred[0][tid] + lred[1][tid] + lred[2][tid] + lred[3][tid];
        outlp[((size_t)split * B_ + b) * N_ + i0 + tid] = l;
    }
}

// ---------- final: sum split partials, divide, ELU
__global__ __launch_bounds__(256) void finalize2_kernel(
    const float* __restrict__ outp, const float* __restrict__ outlp,
    float* __restrict__ out)
{
    const int id = blockIdx.x * 256 + threadIdx.x;      // B*N*EN
    const int gi = id >> 4;
    float num = 0.f, l = 0.f;
#pragma unroll
    for (int s = 0; s < S2_; ++s) {
        num += outp[(size_t)s * B_ * N_ * EN_ + id];
        l   += outlp[(size_t)s * B_ * N_ + gi];
    }
    float v = num / fmaxf(l, 1e-30f);
    out[id] = v > 0.f ? v : expm1f(v);
}

extern "C" void kernel_launch(void* const* d_in, const int* in_sizes, int n_in,
                              void* d_out, int out_size, void* d_ws, size_t ws_size,
                              hipStream_t stream)
{
    const float* fea = (const float*)d_in[0];
    const float* adj = (const float*)d_in[1];
    const float* Wh  = (const float*)d_in[2];
    const float* ah  = (const float*)d_in[3];
    const float* Wl  = (const float*)d_in[4];
    const float* al  = (const float*)d_in[5];

    float* p = (float*)d_ws;
    float* wh1   = p;  p += (size_t)B_ * H_ * N_;            // 32768
    float* wh2   = p;  p += (size_t)B_ * H_ * N_;            // 32768
    float* wh1b  = p;  p += (size_t)B_ * N_;                 // 8192
    float* wh2b  = p;  p += (size_t)B_ * N_;                 // 8192
    float* cmax1 = p;  p += (size_t)B_ * H_ * 512;           // 4096
    float* cmax2 = p;  p += (size_t)B_ * 256;                // 512
    float* l1p   = p;  p += (size_t)S1_ * B_ * N_ * H_;      // 131072
    float* x2p   = p;  p += (size_t)S1_ * B_ * N_ * D_;      // 4194304
    float* outp  = p;  p += (size_t)S2_ * B_ * N_ * EN_;     // 524288
    float* outlp = p;  p += (size_t)S2_ * B_ * N_;           // 32768
    unsigned long long* mask = (unsigned long long*)p;       // B*N*64 u64 = 4 MB
    unsigned short* whTt  = (unsigned short*)(mask + (size_t)B_ * N_ * 64);  // 2 MB
    unsigned short* whT2t = whTt + (size_t)B_ * H_ * 131072;                 // 256 KB

    maskc_kernel<<<dim3(N_ / 4, B_), 256, 0, stream>>>(adj, mask);
    proj1_kernel<<<dim3(N_ / 8, H_, B_), 256, 0, stream>>>(fea, Wh, ah,
                                                           wh1, wh2, cmax1, whTt);
    attn1_kernel<<<dim3(N_ / 16, S1_, B_), 256, 0, stream>>>(mask, whTt, wh1, wh2, cmax1,
                                                             x2p, l1p);
    proj2_kernel<<<dim3(N_ / 16, B_), 256, 0, stream>>>(x2p, l1p, Wl, al,
                                                        wh1b, wh2b, cmax2, whT2t);
    attn2_kernel<<<dim3(N_ / 16, S2_, B_), 256, 0, stream>>>(mask, whT2t, wh1b, wh2b, cmax2,
                                                             outp, outlp);
    finalize2_kernel<<<(B_ * N_ * EN_) / 256, 256, 0, stream>>>(outp, outlp, (float*)d_out);
}

// Round 12
// 287.552 us; speedup vs baseline: 1.2461x; 1.1148x over previous
//
#include <hip/hip_runtime.h>
#include <hip/hip_bf16.h>
#include <stdint.h>

#define B_ 2
#define N_ 4096
#define D_ 128
#define H_ 4
#define HID_ 32
#define EN_ 16
#define ALPHA_ 0.2f
#define S1_ 4
#define S2_ 4
#define LOG2E_ 1.4426950408889634f

typedef __attribute__((ext_vector_type(8))) _Float16 f16x8;
typedef __attribute__((ext_vector_type(4))) float f32x4;
typedef __attribute__((ext_vector_type(8))) unsigned short u16x8;

__device__ __forceinline__ unsigned short f2h(float v) {
    _Float16 h = (_Float16)v;
    return *(unsigned short*)&h;
}

// ---------- adj -> interleaved bitmask (unchanged)
__global__ __launch_bounds__(256) void maskc_kernel(
    const float* __restrict__ adj, unsigned long long* __restrict__ mask)
{
    const int b = blockIdx.y;
    const int i = blockIdx.x * 4 + (threadIdx.x >> 6);
    const int lane = threadIdx.x & 63;
    const float* ar = adj + ((size_t)b * N_ + i) * N_;
    unsigned long long* mrow = mask + ((size_t)b * N_ + i) * 64;
#pragma unroll 4
    for (int c = 0; c < 16; ++c) {
        float4 v = *(const float4*)(ar + c * 256 + lane * 4);
        unsigned long long b0 = __ballot(v.x != 0.f);
        unsigned long long b1 = __ballot(v.y != 0.f);
        unsigned long long b2 = __ballot(v.z != 0.f);
        unsigned long long b3 = __ballot(v.w != 0.f);
        if (lane == 0) {
            ulonglong2 w01 = {b0, b1}, w23 = {b2, b3};
            *(ulonglong2*)(mrow + c * 4) = w01;
            *(ulonglong2*)(mrow + c * 4 + 2) = w23;
        }
    }
}

// ---------- layer-1 projection, register-tiled: 64 rows x 32 cols per block (one head).
// Emits wh1/wh2 = x @ (W@a) (scaled log2e), f16 whT tile, per-block max -> cmax1[64/head].
__global__ __launch_bounds__(256) void proj1_kernel(
    const float* __restrict__ fea, const float* __restrict__ Wh,
    const float* __restrict__ a_heads,
    float* __restrict__ wh1, float* __restrict__ wh2,
    float* __restrict__ cmax1, unsigned short* __restrict__ whTt)
{
    __shared__ float xs[64][132];        // 33.8 KB, pad 132: b128-friendly
    __shared__ float WT[32][132];        // 16.9 KB, WT[d][k]
    __shared__ float Wa[2][128];
    __shared__ float as_[2 * HID_];
    __shared__ unsigned short ts[32 * 64];  // whT staging [d*64 + r]
    __shared__ float rmax[64];
    const int b = blockIdx.z, h = blockIdx.y, i0 = blockIdx.x * 64, tid = threadIdx.x;
    const float* Wp = Wh + (size_t)h * D_ * HID_;
    for (int l = tid; l < 1024; l += 256) {          // W[k][d] -> WT[d][k]
        float4 w4 = *(const float4*)(Wp + l * 4);
        int k = l >> 3, d = (l & 7) * 4;
        WT[d][k] = w4.x; WT[d + 1][k] = w4.y; WT[d + 2][k] = w4.z; WT[d + 3][k] = w4.w;
    }
    if (tid < 2 * HID_) as_[tid] = a_heads[h * 2 * HID_ + tid];
    const float* xp = fea + ((size_t)b * N_ + i0) * D_;
    for (int l = tid; l < 2048; l += 256) {
        int r = l >> 5, k4 = (l & 31) * 4;
        *(float4*)&xs[r][k4] = *(const float4*)(xp + r * D_ + k4);
    }
    __syncthreads();
    // Wa[j][k] = sum_d W[k][d]*a[j*HID+d]  (global W rows, L2-hot)
    {
        const int k = tid & 127, j = tid >> 7;
        const float* wr = Wp + k * HID_;
        const float* aw = &as_[j * HID_];
        float s = 0.f;
#pragma unroll
        for (int d = 0; d < HID_; d += 4) {
            float4 w4 = *(const float4*)(wr + d);
            s += w4.x * aw[d] + w4.y * aw[d + 1] + w4.z * aw[d + 2] + w4.w * aw[d + 3];
        }
        Wa[j][k] = s;
    }
    // main: rows rg..rg+3, cols c and c+16 (stride-16 pair: conflict-free WT reads)
    const int rg = (tid >> 4) * 4, c = tid & 15;
    float a0[4] = {0.f, 0.f, 0.f, 0.f}, a1[4] = {0.f, 0.f, 0.f, 0.f};
#pragma unroll 8
    for (int k = 0; k < D_; k += 4) {
        float4 w0 = *(float4*)&WT[c][k];
        float4 w1 = *(float4*)&WT[c + 16][k];
#pragma unroll
        for (int i = 0; i < 4; ++i) {
            float4 x4 = *(float4*)&xs[rg + i][k];
            a0[i] += x4.x * w0.x + x4.y * w0.y + x4.z * w0.z + x4.w * w0.w;
            a1[i] += x4.x * w1.x + x4.y * w1.y + x4.z * w1.z + x4.w * w1.w;
        }
    }
#pragma unroll
    for (int i = 0; i < 4; ++i) {
        ts[c * 64 + rg + i] = f2h(a0[i]);
        ts[(c + 16) * 64 + rg + i] = f2h(a1[i]);
    }
    __syncthreads();                                 // Wa ready
    {
        const int row = tid >> 2, q = tid & 3;
        float d1 = 0.f, d2 = 0.f;
#pragma unroll
        for (int k = q * 32; k < q * 32 + 32; k += 4) {
            float4 x4 = *(float4*)&xs[row][k];
            float4 u = *(float4*)&Wa[0][k];
            float4 v = *(float4*)&Wa[1][k];
            d1 += x4.x * u.x + x4.y * u.y + x4.z * u.z + x4.w * u.w;
            d2 += x4.x * v.x + x4.y * v.y + x4.z * v.z + x4.w * v.w;
        }
        d1 += __shfl_xor(d1, 1); d1 += __shfl_xor(d1, 2);
        d2 += __shfl_xor(d2, 1); d2 += __shfl_xor(d2, 2);
        if (q == 0) {
            const size_t o = (size_t)(b * H_ + h) * N_ + i0 + row;
            wh1[o] = d1 * LOG2E_;
            wh2[o] = d2 * LOG2E_;
            rmax[row] = d2 * LOG2E_;
        }
    }
    __syncthreads();                                 // ts + rmax complete
    {
        unsigned short* dst = whTt + ((size_t)(b * H_ + h) * 64 + blockIdx.x) * 2048;
        *(u16x8*)(dst + tid * 8) = *(u16x8*)&ts[tid * 8];
    }
    if (tid < 64) {
        float mx = rmax[tid];
#pragma unroll
        for (int off = 32; off; off >>= 1) mx = fmaxf(mx, __shfl_xor(mx, off));
        if (tid == 0) cmax1[(size_t)(b * H_ + h) * 64 + blockIdx.x] = mx;
    }
}

// ---------- layer-1 fused MFMA attention: 32 rows/block (2 row-tiles/wave share
// V-frags + w2 -> L2 traffic halved), bitmask-gated, atomic-free, split-K=4.
__global__ __launch_bounds__(256, 4) void attn1_kernel(
    const unsigned long long* __restrict__ mask, const unsigned short* __restrict__ whT,
    const float* __restrict__ wh1, const float* __restrict__ wh2,
    const float* __restrict__ cmax1,
    float* __restrict__ x2p, float* __restrict__ l1p)
{
    __shared__ unsigned long long mask_s[32][17];
    const int b = blockIdx.z, split = blockIdx.y, i0 = blockIdx.x * 32;
    const int tid = threadIdx.x, lane = tid & 63, h = tid >> 6;
    const int m = lane & 15, quad = lane >> 4;
    {
        const int r = tid >> 3, w = (tid & 7) * 2;
        ulonglong2 mw = *(const ulonglong2*)(mask + ((size_t)b * N_ + i0 + r) * 64
                                             + split * 16 + w);
        mask_s[r][w] = mw.x; mask_s[r][w + 1] = mw.y;
    }
    const float* cm = cmax1 + (size_t)(b * H_ + h) * 64;
    float Mh = cm[lane];
#pragma unroll
    for (int off = 32; off; off >>= 1) Mh = fmaxf(Mh, __shfl_xor(Mh, off));
    const size_t bhN = (size_t)(b * H_ + h) * N_;
    const float w1r0 = wh1[bhN + i0 + m];
    const float w1r1 = wh1[bhN + i0 + 16 + m];
    const float sb0 = w1r0 + Mh, sb1 = w1r1 + Mh;
    const float mr0 = fmaxf(sb0, ALPHA_ * sb0);
    const float mr1 = fmaxf(sb1, ALPHA_ * sb1);
    const float* wvb = wh2 + bhN + split * 1024 + quad * 8;
    const unsigned short* bpb = whT + (size_t)(b * H_ + h) * 131072
                              + (size_t)split * 16 * 2048 + m * 64 + quad * 8;
    f32x4 a00 = {0.f,0.f,0.f,0.f}, a01 = {0.f,0.f,0.f,0.f}, a02 = {0.f,0.f,0.f,0.f};
    f32x4 a10 = {0.f,0.f,0.f,0.f}, a11 = {0.f,0.f,0.f,0.f}, a12 = {0.f,0.f,0.f,0.f};
    f16x8 ones;
#pragma unroll
    for (int q = 0; q < 8; ++q) ones[q] = (_Float16)1.0f;
    __syncthreads();

    for (int c = 0; c < 4; ++c) {                    // 4 chunks of 256 j
        const unsigned long long P0 = mask_s[m][c*4+0], P1 = mask_s[m][c*4+1];
        const unsigned long long P2 = mask_s[m][c*4+2], P3 = mask_s[m][c*4+3];
        const unsigned long long Q0 = mask_s[m+16][c*4+0], Q1 = mask_s[m+16][c*4+1];
        const unsigned long long Q2 = mask_s[m+16][c*4+2], Q3 = mask_s[m+16][c*4+3];
#pragma unroll
        for (int q4 = 0; q4 < 4; ++q4) {
            const int t = c * 4 + q4;
            const unsigned short* bp = bpb + (size_t)t * 2048;
            f16x8 b00 = *(const f16x8*)bp;           // ks0, d=m
            f16x8 b10 = *(const f16x8*)(bp + 32);    // ks1, d=m
            f16x8 b01 = *(const f16x8*)(bp + 1024);  // ks0, d=m+16
            f16x8 b11 = *(const f16x8*)(bp + 1056);
            const float* nw = wvb + t * 64;
            float4 u0 = *(const float4*)nw;
            float4 u1 = *(const float4*)(nw + 4);
            float4 v0 = *(const float4*)(nw + 32);
            float4 v1 = *(const float4*)(nw + 36);
#pragma unroll
            for (int ks = 0; ks < 2; ++ks) {
                const int sh = 16 * q4 + 8 * ks + 2 * quad;
                float wv8[8];
                if (ks == 0) { *(float4*)&wv8[0] = u0; *(float4*)&wv8[4] = u1; }
                else         { *(float4*)&wv8[0] = v0; *(float4*)&wv8[4] = v1; }
                const unsigned int gp0 = (unsigned int)(P0 >> sh) & 3u;
                const unsigned int gp1 = (unsigned int)(P1 >> sh) & 3u;
                const unsigned int gp2 = (unsigned int)(P2 >> sh) & 3u;
                const unsigned int gp3 = (unsigned int)(P3 >> sh) & 3u;
                const unsigned int gq0 = (unsigned int)(Q0 >> sh) & 3u;
                const unsigned int gq1 = (unsigned int)(Q1 >> sh) & 3u;
                const unsigned int gq2 = (unsigned int)(Q2 >> sh) & 3u;
                const unsigned int gq3 = (unsigned int)(Q3 >> sh) & 3u;
                f16x8 af0, af1;
#pragma unroll
                for (int qq = 0; qq < 4; ++qq) {
                    float r0p[2], r1p[2];
#pragma unroll
                    for (int cc = 0; cc < 2; ++cc) {
                        const int jj = qq * 2 + cc;
                        const unsigned int bsel = 1u << (jj >> 2);
                        const unsigned int gp = (jj&3)==0?gp0:(jj&3)==1?gp1:(jj&3)==2?gp2:gp3;
                        const unsigned int gq = (jj&3)==0?gq0:(jj&3)==1?gq1:(jj&3)==2?gq2:gq3;
                        float s0 = w1r0 + wv8[jj];
                        float e0 = fmaxf(s0, ALPHA_ * s0);
                        float t0 = ((gp & bsel) == 0u || s0 == 0.f) ? -1e38f : (e0 - mr0);
                        r0p[cc] = __builtin_amdgcn_exp2f(t0);
                        float s1 = w1r1 + wv8[jj];
                        float e1 = fmaxf(s1, ALPHA_ * s1);
                        float t1 = ((gq & bsel) == 0u || s1 == 0.f) ? -1e38f : (e1 - mr1);
                        r1p[cc] = __builtin_amdgcn_exp2f(t1);
                    }
                    auto pr0 = __builtin_amdgcn_cvt_pkrtz(r0p[0], r0p[1]);
                    af0[qq*2] = (_Float16)pr0[0]; af0[qq*2+1] = (_Float16)pr0[1];
                    auto pr1 = __builtin_amdgcn_cvt_pkrtz(r1p[0], r1p[1]);
                    af1[qq*2] = (_Float16)pr1[0]; af1[qq*2+1] = (_Float16)pr1[1];
                }
                f16x8 bb0 = ks ? b10 : b00;
                f16x8 bb1 = ks ? b11 : b01;
                a00 = __builtin_amdgcn_mfma_f32_16x16x32_f16(af0, bb0, a00, 0, 0, 0);
                a01 = __builtin_amdgcn_mfma_f32_16x16x32_f16(af0, bb1, a01, 0, 0, 0);
                a02 = __builtin_amdgcn_mfma_f32_16x16x32_f16(af0, ones, a02, 0, 0, 0);
                a10 = __builtin_amdgcn_mfma_f32_16x16x32_f16(af1, bb0, a10, 0, 0, 0);
                a11 = __builtin_amdgcn_mfma_f32_16x16x32_f16(af1, bb1, a11, 0, 0, 0);
                a12 = __builtin_amdgcn_mfma_f32_16x16x32_f16(af1, ones, a12, 0, 0, 0);
            }
        }
    }
    float* xp = x2p + (((size_t)split * B_ + b) * N_ + i0) * D_ + h * HID_;
#pragma unroll
    for (int reg = 0; reg < 4; ++reg) {
        const int row = quad * 4 + reg;              // C/D: col=lane&15, row=quad*4+reg
        xp[(size_t)row * D_ + m] = a00[reg];
        xp[(size_t)row * D_ + 16 + m] = a01[reg];
        xp[(size_t)(row + 16) * D_ + m] = a10[reg];
        xp[(size_t)(row + 16) * D_ + 16 + m] = a11[reg];
    }
    if (m == 0) {
        float* lp = l1p + (((size_t)split * B_ + b) * N_ + i0) * H_ + h;
#pragma unroll
        for (int reg = 0; reg < 4; ++reg) {
            lp[(size_t)(quad * 4 + reg) * H_] = a02[reg];
            lp[(size_t)(quad * 4 + reg + 16) * H_] = a12[reg];
        }
    }
}

// ---------- merged layer-2 projection (unchanged from R11)
__global__ __launch_bounds__(256) void proj2_kernel(
    const float* __restrict__ x2p, const float* __restrict__ l1p,
    const float* __restrict__ Wl, const float* __restrict__ a_last,
    float* __restrict__ wh1b, float* __restrict__ wh2b,
    float* __restrict__ cmax2, unsigned short* __restrict__ whT2t)
{
    __shared__ float Ws[D_ * EN_];
    __shared__ float xs[16][D_];
    __shared__ float as_[2 * EN_];
    __shared__ unsigned short ts[EN_][16];
    __shared__ float rmax[16];
    const int b = blockIdx.y, i0 = blockIdx.x * 16, tid = threadIdx.x;
    for (int idx = tid * 4; idx < D_ * EN_; idx += 1024)
        *(float4*)&Ws[idx] = *(const float4*)(Wl + idx);
    if (tid < 2 * EN_) as_[tid] = a_last[tid];
    for (int idx = tid * 4; idx < 16 * D_; idx += 1024) {
        const int r = idx >> 7, hd = idx & 127, h = hd >> 5;
        float4 v = {0.f, 0.f, 0.f, 0.f};
        float l = 0.f;
#pragma unroll
        for (int s = 0; s < S1_; ++s) {
            const size_t gi = ((size_t)s * B_ + b) * N_ + i0 + r;
            float4 p = *(const float4*)(x2p + gi * D_ + hd);
            v.x += p.x; v.y += p.y; v.z += p.z; v.w += p.w;
            l += l1p[gi * H_ + h];
        }
        float linv = 1.f / fmaxf(l, 1e-30f);
        float o0 = v.x * linv, o1 = v.y * linv, o2 = v.z * linv, o3 = v.w * linv;
        xs[r][hd]     = o0 > 0.f ? o0 : expm1f(o0);
        xs[r][hd + 1] = o1 > 0.f ? o1 : expm1f(o1);
        xs[r][hd + 2] = o2 > 0.f ? o2 : expm1f(o2);
        xs[r][hd + 3] = o3 > 0.f ? o3 : expm1f(o3);
    }
    __syncthreads();
    const int r = tid >> 4, e = tid & 15;
    float acc = 0.f;
#pragma unroll 8
    for (int k = 0; k < D_; ++k) acc += xs[r][k] * Ws[k * EN_ + e];
    ts[e][r] = f2h(acc);
    float d1 = acc * as_[e], d2 = acc * as_[EN_ + e];
#pragma unroll
    for (int off = 8; off; off >>= 1) {
        d1 += __shfl_xor(d1, off);
        d2 += __shfl_xor(d2, off);
    }
    d1 *= LOG2E_; d2 *= LOG2E_;
    if (e == 0) {
        wh1b[(size_t)b * N_ + i0 + r] = d1;
        wh2b[(size_t)b * N_ + i0 + r] = d2;
        rmax[r] = d2;
    }
    __syncthreads();
    if (tid < EN_) {
        unsigned short* dst = whT2t + (size_t)b * 65536
                            + (i0 >> 6) * 1024 + tid * 64 + (i0 & 63);
        *(u16x8*)dst = *(u16x8*)&ts[tid][0];
        *(u16x8*)(dst + 8) = *(u16x8*)&ts[tid][8];
    }
    if (tid == 0) {
        float mx = rmax[0];
#pragma unroll
        for (int k = 1; k < 16; ++k) mx = fmaxf(mx, rmax[k]);
        cmax2[(size_t)b * 256 + blockIdx.x] = mx;
    }
}

// ---------- layer-2 fused MFMA attention (unchanged from R11)
__global__ __launch_bounds__(256) void attn2_kernel(
    const unsigned long long* __restrict__ mask, const unsigned short* __restrict__ whT2,
    const float* __restrict__ wh1b, const float* __restrict__ wh2b,
    const float* __restrict__ cmax2,
    float* __restrict__ outp, float* __restrict__ outlp)
{
    __shared__ unsigned long long mask_s[16][18];
    __shared__ float accred[4][16][17];
    __shared__ float lred[4][16];
    const int b = blockIdx.z, split = blockIdx.y, i0 = blockIdx.x * 16;
    const int tid = threadIdx.x, lane = tid & 63, wv = tid >> 6;
    const int m = lane & 15, quad = lane >> 4;
    mask_s[tid >> 4][tid & 15] =
        mask[((size_t)b * N_ + i0 + (tid >> 4)) * 64 + split * 16 + (tid & 15)];
    const float* cm = cmax2 + (size_t)b * 256;
    float4 c0 = *(const float4*)(cm + lane * 4);
    float Mh = fmaxf(fmaxf(c0.x, c0.y), fmaxf(c0.z, c0.w));
#pragma unroll
    for (int off = 32; off; off >>= 1) Mh = fmaxf(Mh, __shfl_xor(Mh, off));
    const float w1r = wh1b[(size_t)b * N_ + i0 + m];
    const float sbound = w1r + Mh;
    const float mr = fmaxf(sbound, ALPHA_ * sbound);
    const float* w2g = wh2b + (size_t)b * N_;
    const unsigned short* wTg = whT2 + (size_t)b * 65536;
    f32x4 acc = {0.f, 0.f, 0.f, 0.f}, acc2 = {0.f, 0.f, 0.f, 0.f};
    f16x8 ones;
#pragma unroll
    for (int q = 0; q < 8; ++q) ones[q] = (_Float16)1.0f;
    const int jt0 = split * (N_ / S2_);
    __syncthreads();
    unsigned long long W0 = mask_s[m][wv * 4 + 0], W1 = mask_s[m][wv * 4 + 1];
    unsigned long long W2 = mask_s[m][wv * 4 + 2], W3 = mask_s[m][wv * 4 + 3];

    const unsigned short* wTb = wTg + (size_t)(split * 16 + wv * 4) * 1024 + m * 64 + quad * 8;
    const float* wvb = w2g + jt0 + wv * 256 + quad * 8;
#pragma unroll
    for (int q4 = 0; q4 < 4; ++q4) {
        const unsigned short* bp = wTb + (size_t)q4 * 1024;
        f16x8 cb0 = *(const f16x8*)(bp);
        f16x8 cb1 = *(const f16x8*)(bp + 32);
        const float* nw = wvb + q4 * 64;
        float4 cu0 = *(const float4*)(nw);
        float4 cu1 = *(const float4*)(nw + 4);
        float4 cv0 = *(const float4*)(nw + 32);
        float4 cv1 = *(const float4*)(nw + 36);
#pragma unroll
        for (int ks = 0; ks < 2; ++ks) {
            const int sh = 16 * q4 + 8 * ks + 2 * quad;
            unsigned int g0 = (unsigned int)(W0 >> sh) & 3u;
            unsigned int g1 = (unsigned int)(W1 >> sh) & 3u;
            unsigned int g2 = (unsigned int)(W2 >> sh) & 3u;
            unsigned int g3 = (unsigned int)(W3 >> sh) & 3u;
            float wv8[8];
            if (ks == 0) { *(float4*)&wv8[0] = cu0; *(float4*)&wv8[4] = cu1; }
            else         { *(float4*)&wv8[0] = cv0; *(float4*)&wv8[4] = cv1; }
            f16x8 af;
#pragma unroll
            for (int q = 0; q < 4; ++q) {
                float p2[2];
#pragma unroll
                for (int cc = 0; cc < 2; ++cc) {
                    const int jj = q * 2 + cc;
                    unsigned int gw = (jj & 3) == 0 ? g0 : (jj & 3) == 1 ? g1
                                    : (jj & 3) == 2 ? g2 : g3;
                    unsigned int bit = gw & (1u << (jj >> 2));
                    float s = w1r + wv8[jj];
                    float e = fmaxf(s, ALPHA_ * s);
                    float tt = (bit == 0u || s == 0.f) ? -1e38f : (e - mr);
                    p2[cc] = __builtin_amdgcn_exp2f(tt);
                }
                auto pr = __builtin_amdgcn_cvt_pkrtz(p2[0], p2[1]);
                af[q * 2] = (_Float16)pr[0]; af[q * 2 + 1] = (_Float16)pr[1];
            }
            acc = __builtin_amdgcn_mfma_f32_16x16x32_f16(af, ks ? cb1 : cb0, acc, 0, 0, 0);
            acc2 = __builtin_amdgcn_mfma_f32_16x16x32_f16(af, ones, acc2, 0, 0, 0);
        }
    }
#pragma unroll
    for (int reg = 0; reg < 4; ++reg)
        accred[wv][quad * 4 + reg][m] = acc[reg];
    if (m == 0) {
#pragma unroll
        for (int reg = 0; reg < 4; ++reg) lred[wv][quad * 4 + reg] = acc2[reg];
    }
    __syncthreads();
    const int row = tid >> 4, col = tid & 15;
    float s = accred[0][row][col] + accred[1][row][col]
            + accred[2][row][col] + accred[3][row][col];
    outp[(((size_t)split * B_ + b) * N_ + i0 + row) * EN_ + col] = s;
    if (tid < 16) {
        float l = lred[0][tid] + lred[1][tid] + lred[2][tid] + lred[3][tid];
        outlp[((size_t)split * B_ + b) * N_ + i0 + tid] = l;
    }
}

// ---------- final: sum split partials, divide, ELU
__global__ __launch_bounds__(256) void finalize2_kernel(
    const float* __restrict__ outp, const float* __restrict__ outlp,
    float* __restrict__ out)
{
    const int id = blockIdx.x * 256 + threadIdx.x;      // B*N*EN
    const int gi = id >> 4;
    float num = 0.f, l = 0.f;
#pragma unroll
    for (int s = 0; s < S2_; ++s) {
        num += outp[(size_t)s * B_ * N_ * EN_ + id];
        l   += outlp[(size_t)s * B_ * N_ + gi];
    }
    float v = num / fmaxf(l, 1e-30f);
    out[id] = v > 0.f ? v : expm1f(v);
}

extern "C" void kernel_launch(void* const* d_in, const int* in_sizes, int n_in,
                              void* d_out, int out_size, void* d_ws, size_t ws_size,
                              hipStream_t stream)
{
    const float* fea = (const float*)d_in[0];
    const float* adj = (const float*)d_in[1];
    const float* Wh  = (const float*)d_in[2];
    const float* ah  = (const float*)d_in[3];
    const float* Wl  = (const float*)d_in[4];
    const float* al  = (const float*)d_in[5];

    float* p = (float*)d_ws;
    float* wh1   = p;  p += (size_t)B_ * H_ * N_;            // 32768
    float* wh2   = p;  p += (size_t)B_ * H_ * N_;            // 32768
    float* wh1b  = p;  p += (size_t)B_ * N_;                 // 8192
    float* wh2b  = p;  p += (size_t)B_ * N_;                 // 8192
    float* cmax1 = p;  p += (size_t)B_ * H_ * 64;            // 512
    float* cmax2 = p;  p += (size_t)B_ * 256;                // 512
    float* l1p   = p;  p += (size_t)S1_ * B_ * N_ * H_;      // 131072
    float* x2p   = p;  p += (size_t)S1_ * B_ * N_ * D_;      // 4194304
    float* outp  = p;  p += (size_t)S2_ * B_ * N_ * EN_;     // 524288
    float* outlp = p;  p += (size_t)S2_ * B_ * N_;           // 32768
    unsigned long long* mask = (unsigned long long*)p;       // B*N*64 u64 = 4 MB
    unsigned short* whTt  = (unsigned short*)(mask + (size_t)B_ * N_ * 64);  // 2 MB
    unsigned short* whT2t = whTt + (size_t)B_ * H_ * 131072;                 // 256 KB

    maskc_kernel<<<dim3(N_ / 4, B_), 256, 0, stream>>>(adj, mask);
    proj1_kernel<<<dim3(N_ / 64, H_, B_), 256, 0, stream>>>(fea, Wh, ah,
                                                            wh1, wh2, cmax1, whTt);
    attn1_kernel<<<dim3(N_ / 32, S1_, B_), 256, 0, stream>>>(mask, whTt, wh1, wh2, cmax1,
                                                             x2p, l1p);
    proj2_kernel<<<dim3(N_ / 16, B_), 256, 0, stream>>>(x2p, l1p, Wl, al,
                                                        wh1b, wh2b, cmax2, whT2t);
    attn2_kernel<<<dim3(N_ / 16, S2_, B_), 256, 0, stream>>>(mask, whT2t, wh1b, wh2b, cmax2,
                                                             outp, outlp);
    finalize2_kernel<<<(B_ * N_ * EN_) / 256, 256, 0, stream>>>(outp, outlp, (float*)d_out);
}

// Round 13
// 282.755 us; speedup vs baseline: 1.2673x; 1.0170x over previous
//
#include <hip/hip_runtime.h>
#include <hip/hip_bf16.h>
#include <stdint.h>

#define B_ 2
#define N_ 4096
#define D_ 128
#define H_ 4
#define HID_ 32
#define EN_ 16
#define ALPHA_ 0.2f
#define S1_ 4
#define S2_ 4
#define LOG2E_ 1.4426950408889634f

typedef __attribute__((ext_vector_type(8))) _Float16 f16x8;
typedef __attribute__((ext_vector_type(4))) float f32x4;
typedef __attribute__((ext_vector_type(8))) unsigned short u16x8;

__device__ __forceinline__ unsigned short f2h(float v) {
    _Float16 h = (_Float16)v;
    return *(unsigned short*)&h;
}

// ---------- fused prep: blocks [0,2048) = adj->bitmask; [2048,3072) = layer-1 proj.
// Independent work co-scheduled in one dispatch (HBM stream overlaps VALU GEMM).
__global__ __launch_bounds__(256) void prep_kernel(
    const float* __restrict__ adj, unsigned long long* __restrict__ mask,
    const float* __restrict__ fea, const float* __restrict__ Wh,
    const float* __restrict__ a_heads,
    float* __restrict__ wh1, float* __restrict__ wh2,
    float* __restrict__ cmax1, unsigned short* __restrict__ whTt)
{
    __shared__ float xs[32][132];          // 16.9 KB
    __shared__ float WT[32][132];          // 16.9 KB
    __shared__ float Wa[2][128];
    __shared__ float as_[2 * HID_];
    __shared__ unsigned short ts[32][32];  // [d][r]
    __shared__ float rmax[32];
    const int tid = threadIdx.x;

    if (blockIdx.x < 2048) {               // ---- mask part ----
        const int b = blockIdx.x >> 10, ib = blockIdx.x & 1023;
        const int i = ib * 4 + (tid >> 6);
        const int lane = tid & 63;
        const float* ar = adj + ((size_t)b * N_ + i) * N_;
        unsigned long long* mrow = mask + ((size_t)b * N_ + i) * 64;
#pragma unroll 4
        for (int c = 0; c < 16; ++c) {
            float4 v = *(const float4*)(ar + c * 256 + lane * 4);
            unsigned long long b0 = __ballot(v.x != 0.f);
            unsigned long long b1 = __ballot(v.y != 0.f);
            unsigned long long b2 = __ballot(v.z != 0.f);
            unsigned long long b3 = __ballot(v.w != 0.f);
            if (lane == 0) {
                ulonglong2 w01 = {b0, b1}, w23 = {b2, b3};
                *(ulonglong2*)(mrow + c * 4) = w01;
                *(ulonglong2*)(mrow + c * 4 + 2) = w23;
            }
        }
        return;
    }
    // ---- proj1 part: 32 rows x 32 cols, one head ----
    const int l0 = blockIdx.x - 2048;
    const int ib = l0 & 127, h = (l0 >> 7) & 3, b = l0 >> 9;
    const int i0 = ib * 32;
    const float* Wp = Wh + (size_t)h * D_ * HID_;
    for (int l = tid; l < 1024; l += 256) {          // W[k][d] -> WT[d][k]
        float4 w4 = *(const float4*)(Wp + l * 4);
        int k = l >> 3, d = (l & 7) * 4;
        WT[d][k] = w4.x; WT[d + 1][k] = w4.y; WT[d + 2][k] = w4.z; WT[d + 3][k] = w4.w;
    }
    if (tid < 2 * HID_) as_[tid] = a_heads[h * 2 * HID_ + tid];
    const float* xp = fea + ((size_t)b * N_ + i0) * D_;
    for (int l = tid; l < 1024; l += 256) {
        int r = l >> 5, k4 = (l & 31) * 4;
        *(float4*)&xs[r][k4] = *(const float4*)(xp + r * D_ + k4);
    }
    __syncthreads();
    // Wa[j][k] = sum_d W[k][d]*a[j*HID+d]
    {
        const int k = tid & 127, j = tid >> 7;
        const float* wr = Wp + k * HID_;
        const float* aw = &as_[j * HID_];
        float s = 0.f;
#pragma unroll
        for (int d = 0; d < HID_; d += 4) {
            float4 w4 = *(const float4*)(wr + d);
            s += w4.x * aw[d] + w4.y * aw[d + 1] + w4.z * aw[d + 2] + w4.w * aw[d + 3];
        }
        Wa[j][k] = s;
    }
    const int c = tid & 15, rg = (tid >> 4) * 2;     // rows rg,rg+1; cols c,c+16
    float a0[2] = {0.f, 0.f}, a1[2] = {0.f, 0.f};
#pragma unroll 8
    for (int k = 0; k < D_; k += 4) {
        float4 w0 = *(float4*)&WT[c][k];
        float4 w1 = *(float4*)&WT[c + 16][k];
#pragma unroll
        for (int i = 0; i < 2; ++i) {
            float4 x4 = *(float4*)&xs[rg + i][k];
            a0[i] += x4.x * w0.x + x4.y * w0.y + x4.z * w0.z + x4.w * w0.w;
            a1[i] += x4.x * w1.x + x4.y * w1.y + x4.z * w1.z + x4.w * w1.w;
        }
    }
#pragma unroll
    for (int i = 0; i < 2; ++i) {
        ts[c][rg + i] = f2h(a0[i]);
        ts[c + 16][rg + i] = f2h(a1[i]);
    }
    __syncthreads();                                 // Wa + ts ready
    {
        const int row = tid >> 3, q = tid & 7;       // 32 rows x 8 threads
        float d1 = 0.f, d2 = 0.f;
#pragma unroll
        for (int k = q * 16; k < q * 16 + 16; k += 4) {
            float4 x4 = *(float4*)&xs[row][k];
            float4 u = *(float4*)&Wa[0][k];
            float4 v = *(float4*)&Wa[1][k];
            d1 += x4.x * u.x + x4.y * u.y + x4.z * u.z + x4.w * u.w;
            d2 += x4.x * v.x + x4.y * v.y + x4.z * v.z + x4.w * v.w;
        }
        d1 += __shfl_xor(d1, 1); d1 += __shfl_xor(d1, 2); d1 += __shfl_xor(d1, 4);
        d2 += __shfl_xor(d2, 1); d2 += __shfl_xor(d2, 2); d2 += __shfl_xor(d2, 4);
        if (q == 0) {
            const size_t o = (size_t)(b * H_ + h) * N_ + i0 + row;
            wh1[o] = d1 * LOG2E_;
            wh2[o] = d2 * LOG2E_;
            rmax[row] = d2 * LOG2E_;
        }
    }
    __syncthreads();
    if (tid < 128) {                                 // whT tile out (1024 halfwords)
        const int d = tid >> 2, part = (tid & 3) * 8;
        unsigned short* dst = whTt + ((size_t)(b * H_ + h) * 64 + (i0 >> 6)) * 2048
                            + d * 64 + (i0 & 63) + part;
        *(u16x8*)dst = *(u16x8*)&ts[d][part];
    }
    if (tid < 32) {
        float mx = rmax[tid];
#pragma unroll
        for (int off = 16; off; off >>= 1) mx = fmaxf(mx, __shfl_xor(mx, off));
        if (tid == 0) cmax1[(size_t)(b * H_ + h) * 128 + ib] = mx;
    }
}

// ---------- layer-1 fused MFMA attention (R12 structure; cmax now 128/head)
__global__ __launch_bounds__(256, 4) void attn1_kernel(
    const unsigned long long* __restrict__ mask, const unsigned short* __restrict__ whT,
    const float* __restrict__ wh1, const float* __restrict__ wh2,
    const float* __restrict__ cmax1,
    float* __restrict__ x2p, float* __restrict__ l1p)
{
    __shared__ unsigned long long mask_s[32][17];
    const int b = blockIdx.z, split = blockIdx.y, i0 = blockIdx.x * 32;
    const int tid = threadIdx.x, lane = tid & 63, h = tid >> 6;
    const int m = lane & 15, quad = lane >> 4;
    {
        const int r = tid >> 3, w = (tid & 7) * 2;
        ulonglong2 mw = *(const ulonglong2*)(mask + ((size_t)b * N_ + i0 + r) * 64
                                             + split * 16 + w);
        mask_s[r][w] = mw.x; mask_s[r][w + 1] = mw.y;
    }
    const float* cm = cmax1 + (size_t)(b * H_ + h) * 128;
    float Mh = fmaxf(cm[lane], cm[lane + 64]);
#pragma unroll
    for (int off = 32; off; off >>= 1) Mh = fmaxf(Mh, __shfl_xor(Mh, off));
    const size_t bhN = (size_t)(b * H_ + h) * N_;
    const float w1r0 = wh1[bhN + i0 + m];
    const float w1r1 = wh1[bhN + i0 + 16 + m];
    const float sb0 = w1r0 + Mh, sb1 = w1r1 + Mh;
    const float mr0 = fmaxf(sb0, ALPHA_ * sb0);
    const float mr1 = fmaxf(sb1, ALPHA_ * sb1);
    const float* wvb = wh2 + bhN + split * 1024 + quad * 8;
    const unsigned short* bpb = whT + (size_t)(b * H_ + h) * 131072
                              + (size_t)split * 16 * 2048 + m * 64 + quad * 8;
    f32x4 a00 = {0.f,0.f,0.f,0.f}, a01 = {0.f,0.f,0.f,0.f}, a02 = {0.f,0.f,0.f,0.f};
    f32x4 a10 = {0.f,0.f,0.f,0.f}, a11 = {0.f,0.f,0.f,0.f}, a12 = {0.f,0.f,0.f,0.f};
    f16x8 ones;
#pragma unroll
    for (int q = 0; q < 8; ++q) ones[q] = (_Float16)1.0f;
    __syncthreads();

    for (int c = 0; c < 4; ++c) {
        const unsigned long long P0 = mask_s[m][c*4+0], P1 = mask_s[m][c*4+1];
        const unsigned long long P2 = mask_s[m][c*4+2], P3 = mask_s[m][c*4+3];
        const unsigned long long Q0 = mask_s[m+16][c*4+0], Q1 = mask_s[m+16][c*4+1];
        const unsigned long long Q2 = mask_s[m+16][c*4+2], Q3 = mask_s[m+16][c*4+3];
#pragma unroll
        for (int q4 = 0; q4 < 4; ++q4) {
            const int t = c * 4 + q4;
            const unsigned short* bp = bpb + (size_t)t * 2048;
            f16x8 b00 = *(const f16x8*)bp;
            f16x8 b10 = *(const f16x8*)(bp + 32);
            f16x8 b01 = *(const f16x8*)(bp + 1024);
            f16x8 b11 = *(const f16x8*)(bp + 1056);
            const float* nw = wvb + t * 64;
            float4 u0 = *(const float4*)nw;
            float4 u1 = *(const float4*)(nw + 4);
            float4 v0 = *(const float4*)(nw + 32);
            float4 v1 = *(const float4*)(nw + 36);
#pragma unroll
            for (int ks = 0; ks < 2; ++ks) {
                const int sh = 16 * q4 + 8 * ks + 2 * quad;
                float wv8[8];
                if (ks == 0) { *(float4*)&wv8[0] = u0; *(float4*)&wv8[4] = u1; }
                else         { *(float4*)&wv8[0] = v0; *(float4*)&wv8[4] = v1; }
                const unsigned int gp0 = (unsigned int)(P0 >> sh) & 3u;
                const unsigned int gp1 = (unsigned int)(P1 >> sh) & 3u;
                const unsigned int gp2 = (unsigned int)(P2 >> sh) & 3u;
                const unsigned int gp3 = (unsigned int)(P3 >> sh) & 3u;
                const unsigned int gq0 = (unsigned int)(Q0 >> sh) & 3u;
                const unsigned int gq1 = (unsigned int)(Q1 >> sh) & 3u;
                const unsigned int gq2 = (unsigned int)(Q2 >> sh) & 3u;
                const unsigned int gq3 = (unsigned int)(Q3 >> sh) & 3u;
                f16x8 af0, af1;
#pragma unroll
                for (int qq = 0; qq < 4; ++qq) {
                    float r0p[2], r1p[2];
#pragma unroll
                    for (int cc = 0; cc < 2; ++cc) {
                        const int jj = qq * 2 + cc;
                        const unsigned int bsel = 1u << (jj >> 2);
                        const unsigned int gp = (jj&3)==0?gp0:(jj&3)==1?gp1:(jj&3)==2?gp2:gp3;
                        const unsigned int gq = (jj&3)==0?gq0:(jj&3)==1?gq1:(jj&3)==2?gq2:gq3;
                        float s0 = w1r0 + wv8[jj];
                        float e0 = fmaxf(s0, ALPHA_ * s0);
                        float t0 = ((gp & bsel) == 0u || s0 == 0.f) ? -1e38f : (e0 - mr0);
                        r0p[cc] = __builtin_amdgcn_exp2f(t0);
                        float s1 = w1r1 + wv8[jj];
                        float e1 = fmaxf(s1, ALPHA_ * s1);
                        float t1 = ((gq & bsel) == 0u || s1 == 0.f) ? -1e38f : (e1 - mr1);
                        r1p[cc] = __builtin_amdgcn_exp2f(t1);
                    }
                    auto pr0 = __builtin_amdgcn_cvt_pkrtz(r0p[0], r0p[1]);
                    af0[qq*2] = (_Float16)pr0[0]; af0[qq*2+1] = (_Float16)pr0[1];
                    auto pr1 = __builtin_amdgcn_cvt_pkrtz(r1p[0], r1p[1]);
                    af1[qq*2] = (_Float16)pr1[0]; af1[qq*2+1] = (_Float16)pr1[1];
                }
                f16x8 bb0 = ks ? b10 : b00;
                f16x8 bb1 = ks ? b11 : b01;
                a00 = __builtin_amdgcn_mfma_f32_16x16x32_f16(af0, bb0, a00, 0, 0, 0);
                a01 = __builtin_amdgcn_mfma_f32_16x16x32_f16(af0, bb1, a01, 0, 0, 0);
                a02 = __builtin_amdgcn_mfma_f32_16x16x32_f16(af0, ones, a02, 0, 0, 0);
                a10 = __builtin_amdgcn_mfma_f32_16x16x32_f16(af1, bb0, a10, 0, 0, 0);
                a11 = __builtin_amdgcn_mfma_f32_16x16x32_f16(af1, bb1, a11, 0, 0, 0);
                a12 = __builtin_amdgcn_mfma_f32_16x16x32_f16(af1, ones, a12, 0, 0, 0);
            }
        }
    }
    float* xp = x2p + (((size_t)split * B_ + b) * N_ + i0) * D_ + h * HID_;
#pragma unroll
    for (int reg = 0; reg < 4; ++reg) {
        const int row = quad * 4 + reg;
        xp[(size_t)row * D_ + m] = a00[reg];
        xp[(size_t)row * D_ + 16 + m] = a01[reg];
        xp[(size_t)(row + 16) * D_ + m] = a10[reg];
        xp[(size_t)(row + 16) * D_ + 16 + m] = a11[reg];
    }
    if (m == 0) {
        float* lp = l1p + (((size_t)split * B_ + b) * N_ + i0) * H_ + h;
#pragma unroll
        for (int reg = 0; reg < 4; ++reg) {
            lp[(size_t)(quad * 4 + reg) * H_] = a02[reg];
            lp[(size_t)(quad * 4 + reg + 16) * H_] = a12[reg];
        }
    }
}

// ---------- merged layer-2 projection (unchanged)
__global__ __launch_bounds__(256) void proj2_kernel(
    const float* __restrict__ x2p, const float* __restrict__ l1p,
    const float* __restrict__ Wl, const float* __restrict__ a_last,
    float* __restrict__ wh1b, float* __restrict__ wh2b,
    float* __restrict__ cmax2, unsigned short* __restrict__ whT2t)
{
    __shared__ float Ws[D_ * EN_];
    __shared__ float xs[16][D_];
    __shared__ float as_[2 * EN_];
    __shared__ unsigned short ts[EN_][16];
    __shared__ float rmax[16];
    const int b = blockIdx.y, i0 = blockIdx.x * 16, tid = threadIdx.x;
    for (int idx = tid * 4; idx < D_ * EN_; idx += 1024)
        *(float4*)&Ws[idx] = *(const float4*)(Wl + idx);
    if (tid < 2 * EN_) as_[tid] = a_last[tid];
    for (int idx = tid * 4; idx < 16 * D_; idx += 1024) {
        const int r = idx >> 7, hd = idx & 127, h = hd >> 5;
        float4 v = {0.f, 0.f, 0.f, 0.f};
        float l = 0.f;
#pragma unroll
        for (int s = 0; s < S1_; ++s) {
            const size_t gi = ((size_t)s * B_ + b) * N_ + i0 + r;
            float4 p = *(const float4*)(x2p + gi * D_ + hd);
            v.x += p.x; v.y += p.y; v.z += p.z; v.w += p.w;
            l += l1p[gi * H_ + h];
        }
        float linv = 1.f / fmaxf(l, 1e-30f);
        float o0 = v.x * linv, o1 = v.y * linv, o2 = v.z * linv, o3 = v.w * linv;
        xs[r][hd]     = o0 > 0.f ? o0 : expm1f(o0);
        xs[r][hd + 1] = o1 > 0.f ? o1 : expm1f(o1);
        xs[r][hd + 2] = o2 > 0.f ? o2 : expm1f(o2);
        xs[r][hd + 3] = o3 > 0.f ? o3 : expm1f(o3);
    }
    __syncthreads();
    const int r = tid >> 4, e = tid & 15;
    float acc = 0.f;
#pragma unroll 8
    for (int k = 0; k < D_; ++k) acc += xs[r][k] * Ws[k * EN_ + e];
    ts[e][r] = f2h(acc);
    float d1 = acc * as_[e], d2 = acc * as_[EN_ + e];
#pragma unroll
    for (int off = 8; off; off >>= 1) {
        d1 += __shfl_xor(d1, off);
        d2 += __shfl_xor(d2, off);
    }
    d1 *= LOG2E_; d2 *= LOG2E_;
    if (e == 0) {
        wh1b[(size_t)b * N_ + i0 + r] = d1;
        wh2b[(size_t)b * N_ + i0 + r] = d2;
        rmax[r] = d2;
    }
    __syncthreads();
    if (tid < EN_) {
        unsigned short* dst = whT2t + (size_t)b * 65536
                            + (i0 >> 6) * 1024 + tid * 64 + (i0 & 63);
        *(u16x8*)dst = *(u16x8*)&ts[tid][0];
        *(u16x8*)(dst + 8) = *(u16x8*)&ts[tid][8];
    }
    if (tid == 0) {
        float mx = rmax[0];
#pragma unroll
        for (int k = 1; k < 16; ++k) mx = fmaxf(mx, rmax[k]);
        cmax2[(size_t)b * 256 + blockIdx.x] = mx;
    }
}

// ---------- layer-2 fused MFMA attention: 32 rows/block (2 row-tiles/wave share
// fragments), 4 waves split 1024 j, LDS combine, split-K partial stores.
__global__ __launch_bounds__(256, 4) void attn2_kernel(
    const unsigned long long* __restrict__ mask, const unsigned short* __restrict__ whT2,
    const float* __restrict__ wh1b, const float* __restrict__ wh2b,
    const float* __restrict__ cmax2,
    float* __restrict__ outp, float* __restrict__ outlp)
{
    __shared__ unsigned long long mask_s[32][17];
    __shared__ float accred[4][32][17];
    __shared__ float lred[4][32];
    const int b = blockIdx.z, split = blockIdx.y, i0 = blockIdx.x * 32;
    const int tid = threadIdx.x, lane = tid & 63, wv = tid >> 6;
    const int m = lane & 15, quad = lane >> 4;
    {
        const int r = tid >> 3, w = (tid & 7) * 2;
        ulonglong2 mw = *(const ulonglong2*)(mask + ((size_t)b * N_ + i0 + r) * 64
                                             + split * 16 + w);
        mask_s[r][w] = mw.x; mask_s[r][w + 1] = mw.y;
    }
    const float* cm = cmax2 + (size_t)b * 256;
    float4 c0 = *(const float4*)(cm + lane * 4);
    float Mh = fmaxf(fmaxf(c0.x, c0.y), fmaxf(c0.z, c0.w));
#pragma unroll
    for (int off = 32; off; off >>= 1) Mh = fmaxf(Mh, __shfl_xor(Mh, off));
    const float w1r0 = wh1b[(size_t)b * N_ + i0 + m];
    const float w1r1 = wh1b[(size_t)b * N_ + i0 + 16 + m];
    const float sb0 = w1r0 + Mh, sb1 = w1r1 + Mh;
    const float mr0 = fmaxf(sb0, ALPHA_ * sb0);
    const float mr1 = fmaxf(sb1, ALPHA_ * sb1);
    const unsigned short* wTb = whT2 + (size_t)b * 65536
                              + (size_t)(split * 16 + wv * 4) * 1024 + m * 64 + quad * 8;
    const float* wvb = wh2b + (size_t)b * N_ + split * 1024 + wv * 256 + quad * 8;
    f32x4 a0 = {0.f,0.f,0.f,0.f}, a1 = {0.f,0.f,0.f,0.f};
    f32x4 l0 = {0.f,0.f,0.f,0.f}, l1 = {0.f,0.f,0.f,0.f};
    f16x8 ones;
#pragma unroll
    for (int q = 0; q < 8; ++q) ones[q] = (_Float16)1.0f;
    __syncthreads();
    const unsigned long long P0 = mask_s[m][wv*4+0], P1 = mask_s[m][wv*4+1];
    const unsigned long long P2 = mask_s[m][wv*4+2], P3 = mask_s[m][wv*4+3];
    const unsigned long long Q0 = mask_s[m+16][wv*4+0], Q1 = mask_s[m+16][wv*4+1];
    const unsigned long long Q2 = mask_s[m+16][wv*4+2], Q3 = mask_s[m+16][wv*4+3];
#pragma unroll
    for (int q4 = 0; q4 < 4; ++q4) {
        const unsigned short* bp = wTb + (size_t)q4 * 1024;
        f16x8 cb0 = *(const f16x8*)(bp);
        f16x8 cb1 = *(const f16x8*)(bp + 32);
        const float* nw = wvb + q4 * 64;
        float4 u0 = *(const float4*)(nw);
        float4 u1 = *(const float4*)(nw + 4);
        float4 v0 = *(const float4*)(nw + 32);
        float4 v1 = *(const float4*)(nw + 36);
#pragma unroll
        for (int ks = 0; ks < 2; ++ks) {
            const int sh = 16 * q4 + 8 * ks + 2 * quad;
            float wv8[8];
            if (ks == 0) { *(float4*)&wv8[0] = u0; *(float4*)&wv8[4] = u1; }
            else         { *(float4*)&wv8[0] = v0; *(float4*)&wv8[4] = v1; }
            const unsigned int gp0 = (unsigned int)(P0 >> sh) & 3u;
            const unsigned int gp1 = (unsigned int)(P1 >> sh) & 3u;
            const unsigned int gp2 = (unsigned int)(P2 >> sh) & 3u;
            const unsigned int gp3 = (unsigned int)(P3 >> sh) & 3u;
            const unsigned int gq0 = (unsigned int)(Q0 >> sh) & 3u;
            const unsigned int gq1 = (unsigned int)(Q1 >> sh) & 3u;
            const unsigned int gq2 = (unsigned int)(Q2 >> sh) & 3u;
            const unsigned int gq3 = (unsigned int)(Q3 >> sh) & 3u;
            f16x8 af0, af1;
#pragma unroll
            for (int qq = 0; qq < 4; ++qq) {
                float r0p[2], r1p[2];
#pragma unroll
                for (int cc = 0; cc < 2; ++cc) {
                    const int jj = qq * 2 + cc;
                    const unsigned int bsel = 1u << (jj >> 2);
                    const unsigned int gp = (jj&3)==0?gp0:(jj&3)==1?gp1:(jj&3)==2?gp2:gp3;
                    const unsigned int gq = (jj&3)==0?gq0:(jj&3)==1?gq1:(jj&3)==2?gq2:gq3;
                    float s0 = w1r0 + wv8[jj];
                    float e0 = fmaxf(s0, ALPHA_ * s0);
                    float t0 = ((gp & bsel) == 0u || s0 == 0.f) ? -1e38f : (e0 - mr0);
                    r0p[cc] = __builtin_amdgcn_exp2f(t0);
                    float s1 = w1r1 + wv8[jj];
                    float e1 = fmaxf(s1, ALPHA_ * s1);
                    float t1 = ((gq & bsel) == 0u || s1 == 0.f) ? -1e38f : (e1 - mr1);
                    r1p[cc] = __builtin_amdgcn_exp2f(t1);
                }
                auto pr0 = __builtin_amdgcn_cvt_pkrtz(r0p[0], r0p[1]);
                af0[qq*2] = (_Float16)pr0[0]; af0[qq*2+1] = (_Float16)pr0[1];
                auto pr1 = __builtin_amdgcn_cvt_pkrtz(r1p[0], r1p[1]);
                af1[qq*2] = (_Float16)pr1[0]; af1[qq*2+1] = (_Float16)pr1[1];
            }
            f16x8 bb = ks ? cb1 : cb0;
            a0 = __builtin_amdgcn_mfma_f32_16x16x32_f16(af0, bb, a0, 0, 0, 0);
            l0 = __builtin_amdgcn_mfma_f32_16x16x32_f16(af0, ones, l0, 0, 0, 0);
            a1 = __builtin_amdgcn_mfma_f32_16x16x32_f16(af1, bb, a1, 0, 0, 0);
            l1 = __builtin_amdgcn_mfma_f32_16x16x32_f16(af1, ones, l1, 0, 0, 0);
        }
    }
#pragma unroll
    for (int reg = 0; reg < 4; ++reg) {
        accred[wv][quad * 4 + reg][m] = a0[reg];
        accred[wv][quad * 4 + reg + 16][m] = a1[reg];
    }
    if (m == 0) {
#pragma unroll
        for (int reg = 0; reg < 4; ++reg) {
            lred[wv][quad * 4 + reg] = l0[reg];
            lred[wv][quad * 4 + reg + 16] = l1[reg];
        }
    }
    __syncthreads();
    const int row = tid >> 4, col = tid & 15;
    float s0 = accred[0][row][col] + accred[1][row][col]
             + accred[2][row][col] + accred[3][row][col];
    float s1 = accred[0][row + 16][col] + accred[1][row + 16][col]
             + accred[2][row + 16][col] + accred[3][row + 16][col];
    float* op = outp + (((size_t)split * B_ + b) * N_ + i0) * EN_;
    op[(size_t)row * EN_ + col] = s0;
    op[(size_t)(row + 16) * EN_ + col] = s1;
    if (tid < 32) {
        float l = lred[0][tid] + lred[1][tid] + lred[2][tid] + lred[3][tid];
        outlp[((size_t)split * B_ + b) * N_ + i0 + tid] = l;
    }
}

// ---------- final: sum split partials, divide, ELU
__global__ __launch_bounds__(256) void finalize2_kernel(
    const float* __restrict__ outp, const float* __restrict__ outlp,
    float* __restrict__ out)
{
    const int id = blockIdx.x * 256 + threadIdx.x;      // B*N*EN
    const int gi = id >> 4;
    float num = 0.f, l = 0.f;
#pragma unroll
    for (int s = 0; s < S2_; ++s) {
        num += outp[(size_t)s * B_ * N_ * EN_ + id];
        l   += outlp[(size_t)s * B_ * N_ + gi];
    }
    float v = num / fmaxf(l, 1e-30f);
    out[id] = v > 0.f ? v : expm1f(v);
}

extern "C" void kernel_launch(void* const* d_in, const int* in_sizes, int n_in,
                              void* d_out, int out_size, void* d_ws, size_t ws_size,
                              hipStream_t stream)
{
    const float* fea = (const float*)d_in[0];
    const float* adj = (const float*)d_in[1];
    const float* Wh  = (const float*)d_in[2];
    const float* ah  = (const float*)d_in[3];
    const float* Wl  = (const float*)d_in[4];
    const float* al  = (const float*)d_in[5];

    float* p = (float*)d_ws;
    float* wh1   = p;  p += (size_t)B_ * H_ * N_;            // 32768
    float* wh2   = p;  p += (size_t)B_ * H_ * N_;            // 32768
    float* wh1b  = p;  p += (size_t)B_ * N_;                 // 8192
    float* wh2b  = p;  p += (size_t)B_ * N_;                 // 8192
    float* cmax1 = p;  p += (size_t)B_ * H_ * 128;           // 1024
    float* cmax2 = p;  p += (size_t)B_ * 256;                // 512
    float* l1p   = p;  p += (size_t)S1_ * B_ * N_ * H_;      // 131072
    float* x2p   = p;  p += (size_t)S1_ * B_ * N_ * D_;      // 4194304
    float* outp  = p;  p += (size_t)S2_ * B_ * N_ * EN_;     // 524288
    float* outlp = p;  p += (size_t)S2_ * B_ * N_;           // 32768
    unsigned long long* mask = (unsigned long long*)p;       // B*N*64 u64 = 4 MB
    unsigned short* whTt  = (unsigned short*)(mask + (size_t)B_ * N_ * 64);  // 2 MB
    unsigned short* whT2t = whTt + (size_t)B_ * H_ * 131072;                 // 256 KB

    prep_kernel<<<2048 + B_ * H_ * 128, 256, 0, stream>>>(adj, mask, fea, Wh, ah,
                                                          wh1, wh2, cmax1, whTt);
    attn1_kernel<<<dim3(N_ / 32, S1_, B_), 256, 0, stream>>>(mask, whTt, wh1, wh2, cmax1,
                                                             x2p, l1p);
    proj2_kernel<<<dim3(N_ / 16, B_), 256, 0, stream>>>(x2p, l1p, Wl, al,
                                                        wh1b, wh2b, cmax2, whT2t);
    attn2_kernel<<<dim3(N_ / 32, S2_, B_), 256, 0, stream>>>(mask, whT2t, wh1b, wh2b, cmax2,
                                                             outp, outlp);
    finalize2_kernel<<<(B_ * N_ * EN_) / 256, 256, 0, stream>>>(outp, outlp, (float*)d_out);
}